// Round 14
// baseline (482.545 us; speedup 1.0000x reference)
//
#include <hip/hip_runtime.h>
#include <hip/hip_bf16.h>

#define HID 256
#define IND 21
#define PB 6400      // edges per block in k_part / bhist
#define MAXB 512     // max buckets (N <= 131072)

typedef short short8 __attribute__((ext_vector_type(8)));
typedef float floatx16 __attribute__((ext_vector_type(16)));
typedef float floatx2 __attribute__((ext_vector_type(2)));

__device__ inline unsigned short f2bf(float f) {
  __hip_bfloat16 h = __float2bfloat16(f);  // RNE
  union { __hip_bfloat16 h; unsigned short u; } c;
  c.h = h;
  return c.u;
}

// pack float2 -> 2 bf16 by truncation (exact for values that came from fp8)
__device__ inline unsigned int pk_bf16_trunc(floatx2 p) {
  union { float f; unsigned int u; } a, b;
  a.f = p.x; b.f = p.y;
  return (b.u & 0xffff0000u) | (a.u >> 16);
}

// accumulate 8 fp8 bytes into 4 packed-f32 accumulators
__device__ inline void acc8p(uint2 v, floatx2* a) {
  a[0] += __builtin_amdgcn_cvt_pk_f32_fp8((int)v.x, false);
  a[1] += __builtin_amdgcn_cvt_pk_f32_fp8((int)v.x, true);
  a[2] += __builtin_amdgcn_cvt_pk_f32_fp8((int)v.y, false);
  a[3] += __builtin_amdgcn_cvt_pk_f32_fp8((int)v.y, true);
}

__device__ inline short8 mk_s8(unsigned a, unsigned b, unsigned c, unsigned d) {
  union { uint4 u; short8 s; } x; x.u = make_uint4(a, b, c, d); return x.s;
}

// decode 8 fp8 bytes (uint2) -> short8 of bf16 (exact)
__device__ inline short8 dec8(uint2 v) {
  unsigned w0 = pk_bf16_trunc(__builtin_amdgcn_cvt_pk_f32_fp8((int)v.x, false));
  unsigned w1 = pk_bf16_trunc(__builtin_amdgcn_cvt_pk_f32_fp8((int)v.x, true));
  unsigned w2 = pk_bf16_trunc(__builtin_amdgcn_cvt_pk_f32_fp8((int)v.y, false));
  unsigned w3 = pk_bf16_trunc(__builtin_amdgcn_cvt_pk_f32_fp8((int)v.y, true));
  return mk_s8(w0, w1, w2, w3);
}

// async global->LDS DMA, 16 B/lane. LDS dest = (uniform) base + lane*16.
__device__ inline void gl16(const unsigned char* g, unsigned char* l) {
  __builtin_amdgcn_global_load_lds(
      (const __attribute__((address_space(1))) unsigned char*)g,
      (__attribute__((address_space(3))) unsigned char*)l, 16, 0, 0);
}

// ---------------------------------------------------------------------------
// fused front kernel: [0,G1) linear_in | [G1,G1+256) wconv | rest bhist
// linear_in writes BOTH row-major xq (k_agg gather source) and
// fragment-linear Aqx (k_h A source, 32x32x16 frag: lane=hi*32+row, 8B/lane).
// wconv writes B fragment-linear:
//   Bf16[((c*8+ct)*64 + lane)*8 + j] = W[c*16+(lane>>5)*8+j][ct*32+(lane&31)]
// ---------------------------------------------------------------------------
__global__ __launch_bounds__(256) void k_front(
    const float* __restrict__ ns, const float* __restrict__ Win,
    const float* __restrict__ bin, unsigned int* __restrict__ xq,
    uint2* __restrict__ Aqx,
    const float* __restrict__ Wself, const float* __restrict__ Wnei,
    unsigned short* __restrict__ Bf16,
    const int* __restrict__ dst, int* __restrict__ bcnt,
    int N, int E, int nb2, int G1) {
  int blk = blockIdx.x;
  int tid = threadIdx.x;
  if (blk < G1) {
    __shared__ float s[8][IND];
    __shared__ float fx[8][257];
    int nb = blk * 8;
    if (tid < 8 * IND) {
      int idx = nb * IND + tid;
      s[tid / IND][tid % IND] = (idx < N * IND) ? ns[idx] : 0.f;
    }
    float w[IND];
#pragma unroll
    for (int k = 0; k < IND; k++) w[k] = Win[k * HID + tid];
    float b = bin[tid];
    __syncthreads();
#pragma unroll
    for (int j = 0; j < 8; j++) {
      float acc = b;
#pragma unroll
      for (int k = 0; k < IND; k++) acc += s[j][k] * w[k];
      fx[j][tid] = acc > 0.f ? acc : 0.f;
    }
    __syncthreads();
    // row-major xq: 2 words per thread
#pragma unroll
    for (int t = 0; t < 2; t++) {
      int wi = tid + t * 256;
      int j = wi >> 6, cw = wi & 63;
      int node = nb + j;
      if (node < N) {
        const float* fp = &fx[j][cw * 4];
        int lo = __builtin_amdgcn_cvt_pk_fp8_f32(fp[0], fp[1], 0, false);
        int full = __builtin_amdgcn_cvt_pk_fp8_f32(fp[2], fp[3], lo, true);
        xq[(size_t)node * 64 + cw] = (unsigned int)full;
      }
    }
    // fragment-linear Aqx: one uint2 (8 fp8) per thread (line-dense per block)
    {
      int j = tid >> 5, u = tid & 31;   // node-local, 8-byte unit (k=u*8..+7)
      int node = nb + j;
      if (node < N) {
        const float* fp = &fx[j][u * 8];
        int lo0 = __builtin_amdgcn_cvt_pk_fp8_f32(fp[0], fp[1], 0, false);
        int w0  = __builtin_amdgcn_cvt_pk_fp8_f32(fp[2], fp[3], lo0, true);
        int lo1 = __builtin_amdgcn_cvt_pk_fp8_f32(fp[4], fp[5], 0, false);
        int w1  = __builtin_amdgcn_cvt_pk_fp8_f32(fp[6], fp[7], lo1, true);
        int g = node >> 5, row = node & 31, c = u >> 1, hi = u & 1;
        Aqx[(size_t)(g * 16 + c) * 64 + hi * 32 + row] =
            make_uint2((unsigned)w0, (unsigned)w1);
      }
    }
  } else if (blk < G1 + 256) {
    int n = blk - G1;           // output column 0..255
    int ct = n >> 5, l5 = n & 31;
#pragma unroll
    for (int t = 0; t < 2; t++) {
      int k = tid + t * 256;    // 0..511
      float v = (k < HID) ? Wself[k * HID + n] : Wnei[(k - HID) * HID + n];
      int c = k >> 4, kin = k & 15;
      int lane = (kin >> 3) * 32 + l5;
      int j = kin & 7;
      Bf16[(size_t)((c * 8 + ct) * 64 + lane) * 8 + j] = f2bf(v);
    }
  } else {
    __shared__ int lh[MAXB];
    int e0 = (blk - G1 - 256) * PB;
    for (int b = tid; b < nb2; b += 256) lh[b] = 0;
    __syncthreads();
    int c = min(PB, E - e0);
    for (int i = tid; i < c; i += 256) atomicAdd(&lh[dst[e0 + i] >> 8], 1);
    __syncthreads();
    for (int b = tid; b < nb2; b += 256)
      if (lh[b]) atomicAdd(&bcnt[b], lh[b]);
  }
}

__global__ __launch_bounds__(512) void k_bscan(
    const int* __restrict__ bcnt, int* __restrict__ bbase, int* __restrict__ bcur,
    int* __restrict__ row_start, int E, int N, int nb2) {
  __shared__ int ts[512];
  int tid = threadIdx.x;
  int v = (tid < nb2) ? bcnt[tid] : 0;
  ts[tid] = v;
  __syncthreads();
  for (int off = 1; off < 512; off <<= 1) {
    int t = (tid >= off) ? ts[tid - off] : 0;
    __syncthreads();
    ts[tid] += t;
    __syncthreads();
  }
  if (tid < nb2) { bbase[tid] = ts[tid] - v; bcur[tid] = ts[tid] - v; }
  if (tid == 0) { bbase[nb2] = E; row_start[N] = E; }
}

// partition edges into per-bucket regions of ebuf (bucket = dst>>8).
// ebuf entry packed: (src << 8) | (dst & 255) -- 4 B/edge.
__global__ __launch_bounds__(256) void k_part(
    const int* __restrict__ src, const int* __restrict__ dst,
    int* __restrict__ bcur, unsigned int* __restrict__ ebuf, int E, int nb2) {
  __shared__ int lh[MAXB];
  int tid = threadIdx.x;
  int e0 = blockIdx.x * PB;
  for (int b = tid; b < nb2; b += 256) lh[b] = 0;
  __syncthreads();
  int cnt = min(PB, E - e0);
  for (int i = tid; i < cnt; i += 256) atomicAdd(&lh[dst[e0 + i] >> 8], 1);
  __syncthreads();
  for (int b = tid; b < nb2; b += 256) {
    int c = lh[b];
    lh[b] = (c > 0) ? atomicAdd(&bcur[b], c) : 0;
  }
  __syncthreads();
  for (int i = tid; i < cnt; i += 256) {
    int s = src[e0 + i];
    int d = dst[e0 + i];
    int pos = atomicAdd(&lh[d >> 8], 1);
    ebuf[pos] = ((unsigned)s << 8) | ((unsigned)d & 255u);
  }
}

// one block per bucket: LDS count + scan -> row_start; LDS cursors -> csr.
__global__ __launch_bounds__(256) void k_fill2(
    const unsigned int* __restrict__ ebuf, const int* __restrict__ bbase,
    int* __restrict__ row_start, int* __restrict__ csr, int N) {
  __shared__ int lcnt[256];
  __shared__ int lcur[256];
  __shared__ int ts[256];
  int b = blockIdx.x;
  int tid = threadIdx.x;
  int start = bbase[b], end = bbase[b + 1];
  lcnt[tid] = 0;
  __syncthreads();
  for (int i = start + tid; i < end; i += 256)
    atomicAdd(&lcnt[ebuf[i] & 255u], 1);
  __syncthreads();
  int v = lcnt[tid];
  ts[tid] = v;
  __syncthreads();
  for (int off = 1; off < 256; off <<= 1) {
    int t = (tid >= off) ? ts[tid - off] : 0;
    __syncthreads();
    ts[tid] += t;
    __syncthreads();
  }
  int excl = start + ts[tid] - v;
  int node = (b << 8) + tid;
  if (node < N) row_start[node] = excl;
  lcur[tid] = excl;
  __syncthreads();
  for (int i = start + tid; i < end; i += 256) {
    unsigned int e = ebuf[i];
    int pos = atomicAdd(&lcur[e & 255u], 1);
    csr[pos] = (int)(e >> 8);
  }
}

// ---------------------------------------------------------------------------
// k_agg: one wave per node; fp8 gather, 8 edges/iter, packed-f32 adds.
// Writes the fp8 mean DENSE row-major (line-dense; no scatter amplification).
// ---------------------------------------------------------------------------
__global__ __launch_bounds__(256) void k_agg(
    const uint2* __restrict__ xq, const int* __restrict__ csr,
    const int* __restrict__ row_start, uint2* __restrict__ aggrm, int N) {
  int wid = (int)((blockIdx.x * (unsigned)blockDim.x + threadIdx.x) >> 6);
  int lane = threadIdx.x & 63;
  int half = lane >> 5;
  int l32 = lane & 31;
  if (wid >= N) return;
  int start = row_start[wid];
  int end = row_start[wid + 1];
  int c = end - start;
  floatx2 a[4], b[4], d[4], e[4];
#pragma unroll
  for (int j = 0; j < 4; j++) {
    a[j] = (floatx2){0.f, 0.f}; b[j] = (floatx2){0.f, 0.f};
    d[j] = (floatx2){0.f, 0.f}; e[j] = (floatx2){0.f, 0.f};
  }
  int i = 0;
  for (; i + 8 <= c; i += 8) {
    int s0 = csr[start + i + half];
    int s1 = csr[start + i + 2 + half];
    int s2 = csr[start + i + 4 + half];
    int s3 = csr[start + i + 6 + half];
    uint2 v0 = xq[(size_t)s0 * 32 + l32];
    uint2 v1 = xq[(size_t)s1 * 32 + l32];
    uint2 v2 = xq[(size_t)s2 * 32 + l32];
    uint2 v3 = xq[(size_t)s3 * 32 + l32];
    acc8p(v0, a); acc8p(v1, b); acc8p(v2, d); acc8p(v3, e);
  }
  for (; i + 2 <= c; i += 2) {
    int s0 = csr[start + i + half];
    uint2 v0 = xq[(size_t)s0 * 32 + l32];
    acc8p(v0, a);
  }
  if ((c & 1) && half == 0) {
    int s0 = csr[start + c - 1];
    uint2 v0 = xq[(size_t)s0 * 32 + l32];
    acc8p(v0, a);
  }
#pragma unroll
  for (int j = 0; j < 4; j++) a[j] += b[j] + d[j] + e[j];

  float f[8];
#pragma unroll
  for (int j = 0; j < 4; j++) { f[2 * j] = a[j].x; f[2 * j + 1] = a[j].y; }
#pragma unroll
  for (int j = 0; j < 8; j++) f[j] += __shfl_xor(f[j], 32);

  if (half == 0) {
    float inv = 1.0f / fmaxf((float)c, 1.0f);
#pragma unroll
    for (int j = 0; j < 8; j++) f[j] *= inv;
    int lo0 = __builtin_amdgcn_cvt_pk_fp8_f32(f[0], f[1], 0, false);
    int w0  = __builtin_amdgcn_cvt_pk_fp8_f32(f[2], f[3], lo0, true);
    int lo1 = __builtin_amdgcn_cvt_pk_fp8_f32(f[4], f[5], 0, false);
    int w1  = __builtin_amdgcn_cvt_pk_fp8_f32(f[6], f[7], lo1, true);
    aggrm[(size_t)wid * 32 + l32] = make_uint2((unsigned)w0, (unsigned)w1);
  }
}

// ---------------------------------------------------------------------------
// k_tr: transpose row-major agg (uint2 per (node,slot)) -> fragment-linear
// Aqagg. 64 nodes (2 groups) per block; coalesced read & write through LDS
// (node stride 33 uint2 -> 2-way banks only).
// ---------------------------------------------------------------------------
__global__ __launch_bounds__(256) void k_tr(
    const uint2* __restrict__ rm, uint2* __restrict__ fr, int N) {
  __shared__ uint2 ld[64 * 33];
  int b = blockIdx.x;
  int tid = threadIdx.x;
  int n0 = b * 64;
#pragma unroll
  for (int j = 0; j < 8; j++) {
    int idx = j * 256 + tid;       // 0..2047
    int nl = idx >> 5, u = idx & 31;
    int node = n0 + nl;
    uint2 v = (node < N) ? rm[(size_t)node * 32 + u] : make_uint2(0u, 0u);
    ld[nl * 33 + u] = v;
  }
  __syncthreads();
  size_t obase = (size_t)b * 2048;   // 2 groups x 1024 uint2
#pragma unroll
  for (int j = 0; j < 8; j++) {
    int oidx = j * 256 + tid;      // 0..2047
    int gg = oidx >> 10, rem = oidx & 1023;
    int c = rem >> 6, hr = rem & 63, hi = hr >> 5, row = hr & 31;
    int nl = gg * 32 + row, u = c * 2 + hi;
    fr[obase + oidx] = ld[nl * 33 + u];
  }
}

// ---------------------------------------------------------------------------
// k_h: block 128 rows x 128 cols (gridDim.y = col half), 4 waves 2x2, wave
// tile 64x64 (acc = 64 regs). BK=64, 8 chunks, LDS double-buffered, one
// barrier per chunk; global_load_lds 1 KB wave-DMAs from fragment-linear
// fp8 A / bf16 B; lane-linear LDS consumes (2-way banks = free).
// Epilogue: per-block colsum partials stored PLAIN (no global atomics);
// k_out reduces.  C/D: col=lane&31, row=(reg&3)+8*(reg>>2)+4*(lane>>5)
// ---------------------------------------------------------------------------
__global__ __launch_bounds__(256, 3) void k_h(
    const unsigned char* __restrict__ Aqx, const unsigned char* __restrict__ Aqagg,
    const unsigned char* __restrict__ Bf8, const float* __restrict__ bself,
    const float* __restrict__ bnei, float* __restrict__ hpart, int N) {
  __shared__ __align__(16) unsigned char As[2][8192];    // 16 KB
  __shared__ __align__(16) unsigned char Bs[2][16384];   // 32 KB
  __shared__ float colsum[128];
  int tid = threadIdx.x;
  int lane = tid & 63;
  int w = tid >> 6;
  int wr = w >> 1, wc = w & 1;
  int l32 = lane & 31, half = lane >> 5;
  int bx = blockIdx.x, by = blockIdx.y;
  int rowBase = bx * 128;

  if (tid < 128) colsum[tid] = 0.f;

  floatx16 acc[2][2];
#pragma unroll
  for (int i = 0; i < 2; i++)
#pragma unroll
    for (int j = 0; j < 2; j++) acc[i][j] = (floatx16)(0.f);

  size_t a_grp = (size_t)(bx * 4 + w) * 16 * 512;
  int lb = lane * 16;

  // prologue: stage chunk 0
  {
    const unsigned char* asrc = Aqx + a_grp + lb;
    gl16(asrc, As[0] + w * 2048);
    gl16(asrc + 1024, As[0] + w * 2048 + 1024);
#pragma unroll
    for (int fi = 0; fi < 4; fi++) {
      int ctg = by * 4 + fi;
      gl16(Bf8 + (size_t)(w * 8 + ctg) * 1024 + lb, Bs[0] + (w * 4 + fi) * 1024);
    }
  }

  for (int ch = 0; ch < 8; ch++) {
    int buf = ch & 1;
    __syncthreads();
    if (ch < 7) {
      int cn = ch + 1;
      const unsigned char* Aq = (cn < 4) ? Aqx : Aqagg;
      const unsigned char* asrc = Aq + a_grp + (size_t)(cn & 3) * 2048 + lb;
      unsigned char* ad = As[buf ^ 1] + w * 2048;
      gl16(asrc, ad);
      gl16(asrc + 1024, ad + 1024);
#pragma unroll
      for (int fi = 0; fi < 4; fi++) {
        int cg = cn * 4 + w;
        int ctg = by * 4 + fi;
        gl16(Bf8 + (size_t)(cg * 8 + ctg) * 1024 + lb,
             Bs[buf ^ 1] + (w * 4 + fi) * 1024);
      }
    }
#pragma unroll
    for (int cl = 0; cl < 4; cl++) {
      short8 afr[2];
#pragma unroll
      for (int rt = 0; rt < 2; rt++) {
        uint2 av = *(const uint2*)&As[buf][(wr * 2 + rt) * 2048 + cl * 512 + lane * 8];
        afr[rt] = dec8(av);
      }
#pragma unroll
      for (int ctw = 0; ctw < 2; ctw++) {
        short8 bfr = *(const short8*)&Bs[buf][(cl * 4 + wc * 2 + ctw) * 1024 + lane * 16];
#pragma unroll
        for (int rt = 0; rt < 2; rt++)
          acc[rt][ctw] = __builtin_amdgcn_mfma_f32_32x32x16_bf16(
              afr[rt], bfr, acc[rt][ctw], 0, 0, 0);
      }
    }
  }

  // epilogue: bias + relu + row-masked column sums -> plain partial store
#pragma unroll
  for (int ctw = 0; ctw < 2; ctw++) {
    int lcol = (wc * 2 + ctw) * 32 + l32;
    int gcol = by * 128 + lcol;
    float bb = bself[gcol] + bnei[gcol];
    float psum = 0.f;
#pragma unroll
    for (int rt = 0; rt < 2; rt++) {
#pragma unroll
      for (int r = 0; r < 16; r++) {
        int rw = rowBase + wr * 64 + rt * 32 + (r & 3) + 8 * (r >> 2) + 4 * half;
        float v = acc[rt][ctw][r] + bb;
        v = v > 0.f ? v : 0.f;
        if (rw < N) psum += v;
      }
    }
    atomicAdd(&colsum[lcol], psum);   // LDS only (2 adds/col)
  }
  __syncthreads();
  if (tid < 128) hpart[(size_t)bx * 256 + by * 128 + tid] = colsum[tid];
}

// ---------------------------------------------------------------------------
// k_out: gsum = sum over partials; out = (gsum/N) @ W_out + b_out
// ---------------------------------------------------------------------------
__global__ __launch_bounds__(HID) void k_out(
    const float* __restrict__ hpart, int nbx,
    const float* __restrict__ Wout, const float* __restrict__ bout,
    float* __restrict__ out, float invN) {
  __shared__ float g[HID];
  int c = threadIdx.x;
  float s = 0.f;
  for (int i = 0; i < nbx; i++) s += hpart[(size_t)i * 256 + c];
  g[c] = s * invN;
  __syncthreads();
  float acc = bout[c];
#pragma unroll 8
  for (int k = 0; k < HID; k++) acc += g[k] * Wout[k * HID + c];
  out[c] = acc;
}

extern "C" void kernel_launch(void* const* d_in, const int* in_sizes, int n_in,
                              void* d_out, int out_size, void* d_ws, size_t ws_size,
                              hipStream_t stream) {
  const float* ns    = (const float*)d_in[0];
  const float* Win   = (const float*)d_in[1];
  const float* bin   = (const float*)d_in[2];
  const float* Wself = (const float*)d_in[3];
  const float* bself = (const float*)d_in[4];
  const float* Wnei  = (const float*)d_in[5];
  const float* bnei  = (const float*)d_in[6];
  const float* Wout  = (const float*)d_in[7];
  const float* bout  = (const float*)d_in[8];
  const int*   eidx  = (const int*)d_in[9];

  int N = in_sizes[0] / IND;
  int E = in_sizes[9] / 2;
  const int* src = eidx;
  const int* dst = eidx + E;
  int nb2 = (N + 255) >> 8;
  int nbx = (N + 127) / 128;                 // k_h row-tiles
  size_t NGU = (size_t)nbx * 4 * 16 * 64;    // fragment uint2 count (padded)

  // ws: xq | Aqx | Aqagg | aggrm | Bf16 | csr | ebuf | row_start | bcnt |
  //     bbase | bcur | hpart
  unsigned int* xq     = (unsigned int*)d_ws;
  uint2* Aqx           = (uint2*)(xq + (size_t)N * 64);
  uint2* Aqagg         = Aqx + NGU;
  uint2* aggrm         = Aqagg + NGU;
  unsigned short* Bf16 = (unsigned short*)(aggrm + (size_t)N * 32);
  int* csr       = (int*)(Bf16 + 256 * 512);
  unsigned int* ebuf = (unsigned int*)(csr + E);
  int* row_start = (int*)(ebuf + E);
  int* bcnt      = row_start + N + 1;
  int* bbase     = bcnt + MAXB;
  int* bcur      = bbase + MAXB + 1;
  float* hpart   = (float*)(bcur + MAXB);

  hipMemsetAsync(bcnt, 0, MAXB * sizeof(int), stream);

  int G1 = (N + 7) / 8;
  int pgrid = (E + PB - 1) / PB;
  k_front<<<G1 + 256 + pgrid, 256, 0, stream>>>(
      ns, Win, bin, xq, Aqx, Wself, Wnei, Bf16, dst, bcnt, N, E, nb2, G1);

  k_bscan<<<1, 512, 0, stream>>>(bcnt, bbase, bcur, row_start, E, N, nb2);
  k_part<<<pgrid, 256, 0, stream>>>(src, dst, bcur, ebuf, E, nb2);
  k_fill2<<<nb2, 256, 0, stream>>>(ebuf, bbase, row_start, csr, N);

  int agrid = (N + 3) / 4;
  k_agg<<<agrid, 256, 0, stream>>>((const uint2*)xq, csr, row_start, aggrm, N);

  int tgrid = (N + 63) / 64;
  k_tr<<<tgrid, 256, 0, stream>>>(aggrm, Aqagg, N);

  dim3 hgrid(nbx, 2);
  k_h<<<hgrid, 256, 0, stream>>>((const unsigned char*)Aqx,
                                 (const unsigned char*)Aqagg,
                                 (const unsigned char*)Bf16,
                                 bself, bnei, hpart, N);

  k_out<<<1, HID, 0, stream>>>(hpart, nbx, Wout, bout, (float*)d_out,
                               1.0f / (float)N);
}

// Round 15
// 316.039 us; speedup vs baseline: 1.5269x; 1.5269x over previous
//
#include <hip/hip_runtime.h>
#include <hip/hip_bf16.h>

#define HID 256
#define IND 21
#define PB 6400      // edges per block in k_part / bhist
#define MAXB 512     // max buckets (N <= 131072)

typedef short short8 __attribute__((ext_vector_type(8)));
typedef float floatx16 __attribute__((ext_vector_type(16)));
typedef float floatx2 __attribute__((ext_vector_type(2)));

__device__ inline unsigned short f2bf(float f) {
  __hip_bfloat16 h = __float2bfloat16(f);  // RNE
  union { __hip_bfloat16 h; unsigned short u; } c;
  c.h = h;
  return c.u;
}

// pack float2 -> 2 bf16 by truncation (exact for values that came from fp8)
__device__ inline unsigned int pk_bf16_trunc(floatx2 p) {
  union { float f; unsigned int u; } a, b;
  a.f = p.x; b.f = p.y;
  return (b.u & 0xffff0000u) | (a.u >> 16);
}

// accumulate 8 fp8 bytes into 4 packed-f32 accumulators
__device__ inline void acc8p(uint2 v, floatx2* a) {
  a[0] += __builtin_amdgcn_cvt_pk_f32_fp8((int)v.x, false);
  a[1] += __builtin_amdgcn_cvt_pk_f32_fp8((int)v.x, true);
  a[2] += __builtin_amdgcn_cvt_pk_f32_fp8((int)v.y, false);
  a[3] += __builtin_amdgcn_cvt_pk_f32_fp8((int)v.y, true);
}

__device__ inline short8 mk_s8(unsigned a, unsigned b, unsigned c, unsigned d) {
  union { uint4 u; short8 s; } x; x.u = make_uint4(a, b, c, d); return x.s;
}

// decode 8 fp8 bytes (uint2) -> short8 of bf16 (exact)
__device__ inline short8 dec8(uint2 v) {
  unsigned w0 = pk_bf16_trunc(__builtin_amdgcn_cvt_pk_f32_fp8((int)v.x, false));
  unsigned w1 = pk_bf16_trunc(__builtin_amdgcn_cvt_pk_f32_fp8((int)v.x, true));
  unsigned w2 = pk_bf16_trunc(__builtin_amdgcn_cvt_pk_f32_fp8((int)v.y, false));
  unsigned w3 = pk_bf16_trunc(__builtin_amdgcn_cvt_pk_f32_fp8((int)v.y, true));
  return mk_s8(w0, w1, w2, w3);
}

// async global->LDS DMA, 16 B/lane. LDS dest = (uniform) base + lane*16.
__device__ inline void gl16(const unsigned char* g, unsigned char* l) {
  __builtin_amdgcn_global_load_lds(
      (const __attribute__((address_space(1))) unsigned char*)g,
      (__attribute__((address_space(3))) unsigned char*)l, 16, 0, 0);
}

// ---------------------------------------------------------------------------
// fused front kernel: [0,G1) linear_in | [G1,G1+256) wconv | rest bhist
// linear_in writes BOTH row-major xq (k_agg gather source) and
// fragment-linear Aqx (k_h A source, 32x32x16 frag: lane=hi*32+row, 8B/lane).
// wconv writes B fragment-linear:
//   Bf16[((c*8+ct)*64 + lane)*8 + j] = W[c*16+(lane>>5)*8+j][ct*32+(lane&31)]
// ---------------------------------------------------------------------------
__global__ __launch_bounds__(256) void k_front(
    const float* __restrict__ ns, const float* __restrict__ Win,
    const float* __restrict__ bin, unsigned int* __restrict__ xq,
    uint2* __restrict__ Aqx,
    const float* __restrict__ Wself, const float* __restrict__ Wnei,
    unsigned short* __restrict__ Bf16,
    const int* __restrict__ dst, int* __restrict__ bcnt,
    int N, int E, int nb2, int G1) {
  int blk = blockIdx.x;
  int tid = threadIdx.x;
  if (blk < G1) {
    __shared__ float s[8][IND];
    __shared__ float fx[8][257];
    int nb = blk * 8;
    if (tid < 8 * IND) {
      int idx = nb * IND + tid;
      s[tid / IND][tid % IND] = (idx < N * IND) ? ns[idx] : 0.f;
    }
    float w[IND];
#pragma unroll
    for (int k = 0; k < IND; k++) w[k] = Win[k * HID + tid];
    float b = bin[tid];
    __syncthreads();
#pragma unroll
    for (int j = 0; j < 8; j++) {
      float acc = b;
#pragma unroll
      for (int k = 0; k < IND; k++) acc += s[j][k] * w[k];
      fx[j][tid] = acc > 0.f ? acc : 0.f;
    }
    __syncthreads();
    // row-major xq: 2 words per thread
#pragma unroll
    for (int t = 0; t < 2; t++) {
      int wi = tid + t * 256;
      int j = wi >> 6, cw = wi & 63;
      int node = nb + j;
      if (node < N) {
        const float* fp = &fx[j][cw * 4];
        int lo = __builtin_amdgcn_cvt_pk_fp8_f32(fp[0], fp[1], 0, false);
        int full = __builtin_amdgcn_cvt_pk_fp8_f32(fp[2], fp[3], lo, true);
        xq[(size_t)node * 64 + cw] = (unsigned int)full;
      }
    }
    // fragment-linear Aqx: one uint2 (8 fp8) per thread (line-dense per block)
    {
      int j = tid >> 5, u = tid & 31;   // node-local, 8-byte unit (k=u*8..+7)
      int node = nb + j;
      if (node < N) {
        const float* fp = &fx[j][u * 8];
        int lo0 = __builtin_amdgcn_cvt_pk_fp8_f32(fp[0], fp[1], 0, false);
        int w0  = __builtin_amdgcn_cvt_pk_fp8_f32(fp[2], fp[3], lo0, true);
        int lo1 = __builtin_amdgcn_cvt_pk_fp8_f32(fp[4], fp[5], 0, false);
        int w1  = __builtin_amdgcn_cvt_pk_fp8_f32(fp[6], fp[7], lo1, true);
        int g = node >> 5, row = node & 31, c = u >> 1, hi = u & 1;
        Aqx[(size_t)(g * 16 + c) * 64 + hi * 32 + row] =
            make_uint2((unsigned)w0, (unsigned)w1);
      }
    }
  } else if (blk < G1 + 256) {
    int n = blk - G1;           // output column 0..255
    int ct = n >> 5, l5 = n & 31;
#pragma unroll
    for (int t = 0; t < 2; t++) {
      int k = tid + t * 256;    // 0..511
      float v = (k < HID) ? Wself[k * HID + n] : Wnei[(k - HID) * HID + n];
      int c = k >> 4, kin = k & 15;
      int lane = (kin >> 3) * 32 + l5;
      int j = kin & 7;
      Bf16[(size_t)((c * 8 + ct) * 64 + lane) * 8 + j] = f2bf(v);
    }
  } else {
    __shared__ int lh[MAXB];
    int e0 = (blk - G1 - 256) * PB;
    for (int b = tid; b < nb2; b += 256) lh[b] = 0;
    __syncthreads();
    int c = min(PB, E - e0);
    for (int i = tid; i < c; i += 256) atomicAdd(&lh[dst[e0 + i] >> 8], 1);
    __syncthreads();
    for (int b = tid; b < nb2; b += 256)
      if (lh[b]) atomicAdd(&bcnt[b], lh[b]);
  }
}

__global__ __launch_bounds__(512) void k_bscan(
    const int* __restrict__ bcnt, int* __restrict__ bbase, int* __restrict__ bcur,
    int* __restrict__ row_start, int E, int N, int nb2) {
  __shared__ int ts[512];
  int tid = threadIdx.x;
  int v = (tid < nb2) ? bcnt[tid] : 0;
  ts[tid] = v;
  __syncthreads();
  for (int off = 1; off < 512; off <<= 1) {
    int t = (tid >= off) ? ts[tid - off] : 0;
    __syncthreads();
    ts[tid] += t;
    __syncthreads();
  }
  if (tid < nb2) { bbase[tid] = ts[tid] - v; bcur[tid] = ts[tid] - v; }
  if (tid == 0) { bbase[nb2] = E; row_start[N] = E; }
}

// partition edges into per-bucket regions of ebuf (bucket = dst>>8).
// ebuf entry packed: (src << 8) | (dst & 255) -- 4 B/edge.
__global__ __launch_bounds__(256) void k_part(
    const int* __restrict__ src, const int* __restrict__ dst,
    int* __restrict__ bcur, unsigned int* __restrict__ ebuf, int E, int nb2) {
  __shared__ int lh[MAXB];
  int tid = threadIdx.x;
  int e0 = blockIdx.x * PB;
  for (int b = tid; b < nb2; b += 256) lh[b] = 0;
  __syncthreads();
  int cnt = min(PB, E - e0);
  for (int i = tid; i < cnt; i += 256) atomicAdd(&lh[dst[e0 + i] >> 8], 1);
  __syncthreads();
  for (int b = tid; b < nb2; b += 256) {
    int c = lh[b];
    lh[b] = (c > 0) ? atomicAdd(&bcur[b], c) : 0;
  }
  __syncthreads();
  for (int i = tid; i < cnt; i += 256) {
    int s = src[e0 + i];
    int d = dst[e0 + i];
    int pos = atomicAdd(&lh[d >> 8], 1);
    ebuf[pos] = ((unsigned)s << 8) | ((unsigned)d & 255u);
  }
}

// one block per bucket: LDS count + scan -> row_start; LDS cursors -> csr.
__global__ __launch_bounds__(256) void k_fill2(
    const unsigned int* __restrict__ ebuf, const int* __restrict__ bbase,
    int* __restrict__ row_start, int* __restrict__ csr, int N) {
  __shared__ int lcnt[256];
  __shared__ int lcur[256];
  __shared__ int ts[256];
  int b = blockIdx.x;
  int tid = threadIdx.x;
  int start = bbase[b], end = bbase[b + 1];
  lcnt[tid] = 0;
  __syncthreads();
  for (int i = start + tid; i < end; i += 256)
    atomicAdd(&lcnt[ebuf[i] & 255u], 1);
  __syncthreads();
  int v = lcnt[tid];
  ts[tid] = v;
  __syncthreads();
  for (int off = 1; off < 256; off <<= 1) {
    int t = (tid >= off) ? ts[tid - off] : 0;
    __syncthreads();
    ts[tid] += t;
    __syncthreads();
  }
  int excl = start + ts[tid] - v;
  int node = (b << 8) + tid;
  if (node < N) row_start[node] = excl;
  lcur[tid] = excl;
  __syncthreads();
  for (int i = start + tid; i < end; i += 256) {
    unsigned int e = ebuf[i];
    int pos = atomicAdd(&lcur[e & 255u], 1);
    csr[pos] = (int)(e >> 8);
  }
}

// ---------------------------------------------------------------------------
// k_agg: one wave per node; fp8 gather, 8 edges/iter, packed-f32 adds.
// Writes the fp8 mean DENSE row-major (line-dense; no scatter amplification).
// ---------------------------------------------------------------------------
__global__ __launch_bounds__(256) void k_agg(
    const uint2* __restrict__ xq, const int* __restrict__ csr,
    const int* __restrict__ row_start, uint2* __restrict__ aggrm, int N) {
  int wid = (int)((blockIdx.x * (unsigned)blockDim.x + threadIdx.x) >> 6);
  int lane = threadIdx.x & 63;
  int half = lane >> 5;
  int l32 = lane & 31;
  if (wid >= N) return;
  int start = row_start[wid];
  int end = row_start[wid + 1];
  int c = end - start;
  floatx2 a[4], b[4], d[4], e[4];
#pragma unroll
  for (int j = 0; j < 4; j++) {
    a[j] = (floatx2){0.f, 0.f}; b[j] = (floatx2){0.f, 0.f};
    d[j] = (floatx2){0.f, 0.f}; e[j] = (floatx2){0.f, 0.f};
  }
  int i = 0;
  for (; i + 8 <= c; i += 8) {
    int s0 = csr[start + i + half];
    int s1 = csr[start + i + 2 + half];
    int s2 = csr[start + i + 4 + half];
    int s3 = csr[start + i + 6 + half];
    uint2 v0 = xq[(size_t)s0 * 32 + l32];
    uint2 v1 = xq[(size_t)s1 * 32 + l32];
    uint2 v2 = xq[(size_t)s2 * 32 + l32];
    uint2 v3 = xq[(size_t)s3 * 32 + l32];
    acc8p(v0, a); acc8p(v1, b); acc8p(v2, d); acc8p(v3, e);
  }
  for (; i + 2 <= c; i += 2) {
    int s0 = csr[start + i + half];
    uint2 v0 = xq[(size_t)s0 * 32 + l32];
    acc8p(v0, a);
  }
  if ((c & 1) && half == 0) {
    int s0 = csr[start + c - 1];
    uint2 v0 = xq[(size_t)s0 * 32 + l32];
    acc8p(v0, a);
  }
#pragma unroll
  for (int j = 0; j < 4; j++) a[j] += b[j] + d[j] + e[j];

  float f[8];
#pragma unroll
  for (int j = 0; j < 4; j++) { f[2 * j] = a[j].x; f[2 * j + 1] = a[j].y; }
#pragma unroll
  for (int j = 0; j < 8; j++) f[j] += __shfl_xor(f[j], 32);

  if (half == 0) {
    float inv = 1.0f / fmaxf((float)c, 1.0f);
#pragma unroll
    for (int j = 0; j < 8; j++) f[j] *= inv;
    int lo0 = __builtin_amdgcn_cvt_pk_fp8_f32(f[0], f[1], 0, false);
    int w0  = __builtin_amdgcn_cvt_pk_fp8_f32(f[2], f[3], lo0, true);
    int lo1 = __builtin_amdgcn_cvt_pk_fp8_f32(f[4], f[5], 0, false);
    int w1  = __builtin_amdgcn_cvt_pk_fp8_f32(f[6], f[7], lo1, true);
    aggrm[(size_t)wid * 32 + l32] = make_uint2((unsigned)w0, (unsigned)w1);
  }
}

// ---------------------------------------------------------------------------
// k_tr: transpose row-major agg -> fragment-linear Aqagg. 64 nodes/block;
// coalesced read & write through LDS (node stride 33 uint2 -> 2-way banks).
// ---------------------------------------------------------------------------
__global__ __launch_bounds__(256) void k_tr(
    const uint2* __restrict__ rm, uint2* __restrict__ fr, int N) {
  __shared__ uint2 ld[64 * 33];
  int b = blockIdx.x;
  int tid = threadIdx.x;
  int n0 = b * 64;
#pragma unroll
  for (int j = 0; j < 8; j++) {
    int idx = j * 256 + tid;       // 0..2047
    int nl = idx >> 5, u = idx & 31;
    int node = n0 + nl;
    uint2 v = (node < N) ? rm[(size_t)node * 32 + u] : make_uint2(0u, 0u);
    ld[nl * 33 + u] = v;
  }
  __syncthreads();
  size_t obase = (size_t)b * 2048;   // 2 groups x 1024 uint2
#pragma unroll
  for (int j = 0; j < 8; j++) {
    int oidx = j * 256 + tid;      // 0..2047
    int gg = oidx >> 10, rem = oidx & 1023;
    int c = rem >> 6, hr = rem & 63, hi = hr >> 5, row = hr & 31;
    int nl = gg * 32 + row, u = c * 2 + hi;
    fr[obase + oidx] = ld[nl * 33 + u];
  }
}

// ---------------------------------------------------------------------------
// k_h: block 128 rows x 128 cols (gridDim.y = col half), 4 waves 2x2, wave
// tile 64x64 (acc = 64 regs). BK=64, 8 chunks, LDS double-buffered, one
// barrier per chunk; global_load_lds 1 KB wave-DMAs from fragment-linear
// fp8 A / bf16 B; lane-linear LDS consumes (2-way banks = free).
// Epilogue: per-block colsum partials stored PLAIN (no global atomics).
// C/D: col=lane&31, row=(reg&3)+8*(reg>>2)+4*(lane>>5)  [m74/m101 verified]
// ---------------------------------------------------------------------------
__global__ __launch_bounds__(256, 3) void k_h(
    const unsigned char* __restrict__ Aqx, const unsigned char* __restrict__ Aqagg,
    const unsigned char* __restrict__ Bf8, const float* __restrict__ bself,
    const float* __restrict__ bnei, float* __restrict__ hpart, int N) {
  __shared__ __align__(16) unsigned char As[2][8192];    // 16 KB
  __shared__ __align__(16) unsigned char Bs[2][16384];   // 32 KB
  __shared__ float colsum[128];
  int tid = threadIdx.x;
  int lane = tid & 63;
  int w = tid >> 6;
  int wr = w >> 1, wc = w & 1;
  int l32 = lane & 31, half = lane >> 5;
  int bx = blockIdx.x, by = blockIdx.y;
  int rowBase = bx * 128;

  if (tid < 128) colsum[tid] = 0.f;

  floatx16 acc[2][2];
#pragma unroll
  for (int i = 0; i < 2; i++)
#pragma unroll
    for (int j = 0; j < 2; j++) acc[i][j] = (floatx16)(0.f);

  size_t a_grp = (size_t)(bx * 4 + w) * 16 * 512;
  int lb = lane * 16;

  // prologue: stage chunk 0
  {
    const unsigned char* asrc = Aqx + a_grp + lb;
    gl16(asrc, As[0] + w * 2048);
    gl16(asrc + 1024, As[0] + w * 2048 + 1024);
#pragma unroll
    for (int fi = 0; fi < 4; fi++) {
      int ctg = by * 4 + fi;
      gl16(Bf8 + (size_t)(w * 8 + ctg) * 1024 + lb, Bs[0] + (w * 4 + fi) * 1024);
    }
  }

  for (int ch = 0; ch < 8; ch++) {
    int buf = ch & 1;
    __syncthreads();
    if (ch < 7) {
      int cn = ch + 1;
      const unsigned char* Aq = (cn < 4) ? Aqx : Aqagg;
      const unsigned char* asrc = Aq + a_grp + (size_t)(cn & 3) * 2048 + lb;
      unsigned char* ad = As[buf ^ 1] + w * 2048;
      gl16(asrc, ad);
      gl16(asrc + 1024, ad + 1024);
#pragma unroll
      for (int fi = 0; fi < 4; fi++) {
        int cg = cn * 4 + w;
        int ctg = by * 4 + fi;
        gl16(Bf8 + (size_t)(cg * 8 + ctg) * 1024 + lb,
             Bs[buf ^ 1] + (w * 4 + fi) * 1024);
      }
    }
#pragma unroll
    for (int cl = 0; cl < 4; cl++) {
      short8 afr[2];
#pragma unroll
      for (int rt = 0; rt < 2; rt++) {
        uint2 av = *(const uint2*)&As[buf][(wr * 2 + rt) * 2048 + cl * 512 + lane * 8];
        afr[rt] = dec8(av);
      }
#pragma unroll
      for (int ctw = 0; ctw < 2; ctw++) {
        short8 bfr = *(const short8*)&Bs[buf][(cl * 4 + wc * 2 + ctw) * 1024 + lane * 16];
#pragma unroll
        for (int rt = 0; rt < 2; rt++)
          acc[rt][ctw] = __builtin_amdgcn_mfma_f32_32x32x16_bf16(
              afr[rt], bfr, acc[rt][ctw], 0, 0, 0);
      }
    }
  }

  // epilogue: bias + relu + row-masked column sums -> plain partial store
#pragma unroll
  for (int ctw = 0; ctw < 2; ctw++) {
    int lcol = (wc * 2 + ctw) * 32 + l32;
    int gcol = by * 128 + lcol;
    float bb = bself[gcol] + bnei[gcol];
    float psum = 0.f;
#pragma unroll
    for (int rt = 0; rt < 2; rt++) {
#pragma unroll
      for (int r = 0; r < 16; r++) {
        int rw = rowBase + wr * 64 + rt * 32 + (r & 3) + 8 * (r >> 2) + 4 * half;
        float v = acc[rt][ctw][r] + bb;
        v = v > 0.f ? v : 0.f;
        if (rw < N) psum += v;
      }
    }
    atomicAdd(&colsum[lcol], psum);   // LDS only (2 adds/col)
  }
  __syncthreads();
  if (tid < 128) hpart[(size_t)bx * 256 + by * 128 + tid] = colsum[tid];
}

// ---------------------------------------------------------------------------
// k_red: parallel reduction of hpart rows -> gsum. Coalesced 1 KB row reads,
// grid-stride; one global atomic per (block, column).
// ---------------------------------------------------------------------------
__global__ __launch_bounds__(256) void k_red(
    const float* __restrict__ hpart, float* __restrict__ gsum, int nbx) {
  int c = threadIdx.x;
  float s = 0.f;
  for (int i = blockIdx.x; i < nbx; i += gridDim.x)
    s += hpart[(size_t)i * 256 + c];
  atomicAdd(&gsum[c], s);
}

// ---------------------------------------------------------------------------
// k_out: out = (gsum / N) @ W_out + b_out   single block, 256 threads
// ---------------------------------------------------------------------------
__global__ __launch_bounds__(HID) void k_out(
    const float* __restrict__ gsum, const float* __restrict__ Wout,
    const float* __restrict__ bout, float* __restrict__ out, float invN) {
  __shared__ float g[HID];
  int c = threadIdx.x;
  g[c] = gsum[c] * invN;
  __syncthreads();
  float acc = bout[c];
#pragma unroll 8
  for (int k = 0; k < HID; k++) acc += g[k] * Wout[k * HID + c];
  out[c] = acc;
}

extern "C" void kernel_launch(void* const* d_in, const int* in_sizes, int n_in,
                              void* d_out, int out_size, void* d_ws, size_t ws_size,
                              hipStream_t stream) {
  const float* ns    = (const float*)d_in[0];
  const float* Win   = (const float*)d_in[1];
  const float* bin   = (const float*)d_in[2];
  const float* Wself = (const float*)d_in[3];
  const float* bself = (const float*)d_in[4];
  const float* Wnei  = (const float*)d_in[5];
  const float* bnei  = (const float*)d_in[6];
  const float* Wout  = (const float*)d_in[7];
  const float* bout  = (const float*)d_in[8];
  const int*   eidx  = (const int*)d_in[9];

  int N = in_sizes[0] / IND;
  int E = in_sizes[9] / 2;
  const int* src = eidx;
  const int* dst = eidx + E;
  int nb2 = (N + 255) >> 8;
  int nbx = (N + 127) / 128;                 // k_h row-tiles
  size_t NGU = (size_t)nbx * 4 * 16 * 64;    // fragment uint2 count (padded)

  // ws: xq | Aqx | Aqagg | aggrm | Bf16 | csr | ebuf | row_start | bcnt |
  //     bbase | bcur | gsum | hpart
  unsigned int* xq     = (unsigned int*)d_ws;
  uint2* Aqx           = (uint2*)(xq + (size_t)N * 64);
  uint2* Aqagg         = Aqx + NGU;
  uint2* aggrm         = Aqagg + NGU;
  unsigned short* Bf16 = (unsigned short*)(aggrm + (size_t)N * 32);
  int* csr       = (int*)(Bf16 + 256 * 512);
  unsigned int* ebuf = (unsigned int*)(csr + E);
  int* row_start = (int*)(ebuf + E);
  int* bcnt      = row_start + N + 1;
  int* bbase     = bcnt + MAXB;
  int* bcur      = bbase + MAXB + 1;
  float* gsum    = (float*)(bcur + MAXB);
  float* hpart   = gsum + HID;

  hipMemsetAsync(bcnt, 0, MAXB * sizeof(int), stream);
  hipMemsetAsync(gsum, 0, HID * sizeof(float), stream);

  int G1 = (N + 7) / 8;
  int pgrid = (E + PB - 1) / PB;
  k_front<<<G1 + 256 + pgrid, 256, 0, stream>>>(
      ns, Win, bin, xq, Aqx, Wself, Wnei, Bf16, dst, bcnt, N, E, nb2, G1);

  k_bscan<<<1, 512, 0, stream>>>(bcnt, bbase, bcur, row_start, E, N, nb2);
  k_part<<<pgrid, 256, 0, stream>>>(src, dst, bcur, ebuf, E, nb2);
  k_fill2<<<nb2, 256, 0, stream>>>(ebuf, bbase, row_start, csr, N);

  int agrid = (N + 3) / 4;
  k_agg<<<agrid, 256, 0, stream>>>((const uint2*)xq, csr, row_start, aggrm, N);

  int tgrid = (N + 63) / 64;
  k_tr<<<tgrid, 256, 0, stream>>>(aggrm, Aqagg, N);

  dim3 hgrid(nbx, 2);
  k_h<<<hgrid, 256, 0, stream>>>((const unsigned char*)Aqx,
                                 (const unsigned char*)Aqagg,
                                 (const unsigned char*)Bf16,
                                 bself, bnei, hpart, N);

  k_red<<<64, 256, 0, stream>>>(hpart, gsum, nbx);
  k_out<<<1, HID, 0, stream>>>(gsum, Wout, bout, (float*)d_out, 1.0f / (float)N);
}

// Round 16
// 310.145 us; speedup vs baseline: 1.5559x; 1.0190x over previous
//
#include <hip/hip_runtime.h>
#include <hip/hip_bf16.h>

#define HID 256
#define IND 21
#define PB 6400      // edges per block in k_part / bhist
#define MAXB 512     // max buckets (N <= 131072)

typedef short short8 __attribute__((ext_vector_type(8)));
typedef float floatx16 __attribute__((ext_vector_type(16)));
typedef float floatx2 __attribute__((ext_vector_type(2)));

__device__ inline unsigned short f2bf(float f) {
  __hip_bfloat16 h = __float2bfloat16(f);  // RNE
  union { __hip_bfloat16 h; unsigned short u; } c;
  c.h = h;
  return c.u;
}

// pack float2 -> 2 bf16 by truncation (exact for values that came from fp8)
__device__ inline unsigned int pk_bf16_trunc(floatx2 p) {
  union { float f; unsigned int u; } a, b;
  a.f = p.x; b.f = p.y;
  return (b.u & 0xffff0000u) | (a.u >> 16);
}

// accumulate 16 fp8 bytes (uint4) into 8 packed-f32 accumulators
__device__ inline void acc16p(uint4 v, floatx2* a) {
  a[0] += __builtin_amdgcn_cvt_pk_f32_fp8((int)v.x, false);
  a[1] += __builtin_amdgcn_cvt_pk_f32_fp8((int)v.x, true);
  a[2] += __builtin_amdgcn_cvt_pk_f32_fp8((int)v.y, false);
  a[3] += __builtin_amdgcn_cvt_pk_f32_fp8((int)v.y, true);
  a[4] += __builtin_amdgcn_cvt_pk_f32_fp8((int)v.z, false);
  a[5] += __builtin_amdgcn_cvt_pk_f32_fp8((int)v.z, true);
  a[6] += __builtin_amdgcn_cvt_pk_f32_fp8((int)v.w, false);
  a[7] += __builtin_amdgcn_cvt_pk_f32_fp8((int)v.w, true);
}

__device__ inline short8 mk_s8(unsigned a, unsigned b, unsigned c, unsigned d) {
  union { uint4 u; short8 s; } x; x.u = make_uint4(a, b, c, d); return x.s;
}

// decode 8 fp8 bytes (uint2) -> short8 of bf16 (exact)
__device__ inline short8 dec8(uint2 v) {
  unsigned w0 = pk_bf16_trunc(__builtin_amdgcn_cvt_pk_f32_fp8((int)v.x, false));
  unsigned w1 = pk_bf16_trunc(__builtin_amdgcn_cvt_pk_f32_fp8((int)v.x, true));
  unsigned w2 = pk_bf16_trunc(__builtin_amdgcn_cvt_pk_f32_fp8((int)v.y, false));
  unsigned w3 = pk_bf16_trunc(__builtin_amdgcn_cvt_pk_f32_fp8((int)v.y, true));
  return mk_s8(w0, w1, w2, w3);
}

// async global->LDS DMA, 16 B/lane. LDS dest = (uniform) base + lane*16.
__device__ inline void gl16(const unsigned char* g, unsigned char* l) {
  __builtin_amdgcn_global_load_lds(
      (const __attribute__((address_space(1))) unsigned char*)g,
      (__attribute__((address_space(3))) unsigned char*)l, 16, 0, 0);
}

// ---------------------------------------------------------------------------
// fused front kernel: [0,G1) linear_in | [G1,G1+256) wconv | rest bhist
// linear_in pack phase: thread = (node j = tid&7, unit u = tid>>3). LDS read
// bank = (j + 8u + i) % 32 -> exactly 2 lanes/bank (free). One uint2 pack
// serves BOTH row-major xq and fragment-linear Aqx; each gets 64 B-dense
// wave writes.
// wconv writes B fragment-linear:
//   Bf16[((c*8+ct)*64 + lane)*8 + j] = W[c*16+(lane>>5)*8+j][ct*32+(lane&31)]
// ---------------------------------------------------------------------------
__global__ __launch_bounds__(256) void k_front(
    const float* __restrict__ ns, const float* __restrict__ Win,
    const float* __restrict__ bin, uint2* __restrict__ xq2,
    uint2* __restrict__ Aqx,
    const float* __restrict__ Wself, const float* __restrict__ Wnei,
    unsigned short* __restrict__ Bf16,
    const int* __restrict__ dst, int* __restrict__ bcnt,
    int N, int E, int nb2, int G1) {
  int blk = blockIdx.x;
  int tid = threadIdx.x;
  if (blk < G1) {
    __shared__ float s[8][IND];
    __shared__ float fx[8][257];
    int nb = blk * 8;
    if (tid < 8 * IND) {
      int idx = nb * IND + tid;
      s[tid / IND][tid % IND] = (idx < N * IND) ? ns[idx] : 0.f;
    }
    float w[IND];
#pragma unroll
    for (int k = 0; k < IND; k++) w[k] = Win[k * HID + tid];
    float b = bin[tid];
    __syncthreads();
#pragma unroll
    for (int j = 0; j < 8; j++) {
      float acc = b;
#pragma unroll
      for (int k = 0; k < IND; k++) acc += s[j][k] * w[k];
      fx[j][tid] = acc > 0.f ? acc : 0.f;
    }
    __syncthreads();
    // pack: one uint2 (8 fp8) per thread -> xq (row-major) + Aqx (fragment)
    {
      int j = tid & 7, u = tid >> 3;    // node-local, 8-col unit 0..31
      int node = nb + j;
      if (node < N) {
        const float* fp = &fx[j][u * 8];
        int lo0 = __builtin_amdgcn_cvt_pk_fp8_f32(fp[0], fp[1], 0, false);
        int w0  = __builtin_amdgcn_cvt_pk_fp8_f32(fp[2], fp[3], lo0, true);
        int lo1 = __builtin_amdgcn_cvt_pk_fp8_f32(fp[4], fp[5], 0, false);
        int w1  = __builtin_amdgcn_cvt_pk_fp8_f32(fp[6], fp[7], lo1, true);
        uint2 val = make_uint2((unsigned)w0, (unsigned)w1);
        xq2[(size_t)node * 32 + u] = val;
        int g = node >> 5, row = node & 31, c = u >> 1, hi = u & 1;
        Aqx[(size_t)(g * 16 + c) * 64 + hi * 32 + row] = val;
      }
    }
  } else if (blk < G1 + 256) {
    int n = blk - G1;           // output column 0..255
    int ct = n >> 5, l5 = n & 31;
#pragma unroll
    for (int t = 0; t < 2; t++) {
      int k = tid + t * 256;    // 0..511
      float v = (k < HID) ? Wself[k * HID + n] : Wnei[(k - HID) * HID + n];
      int c = k >> 4, kin = k & 15;
      int lane = (kin >> 3) * 32 + l5;
      int j = kin & 7;
      Bf16[(size_t)((c * 8 + ct) * 64 + lane) * 8 + j] = f2bf(v);
    }
  } else {
    __shared__ int lh[MAXB];
    int e0 = (blk - G1 - 256) * PB;
    for (int b = tid; b < nb2; b += 256) lh[b] = 0;
    __syncthreads();
    int c = min(PB, E - e0);
    for (int i = tid; i < c; i += 256) atomicAdd(&lh[dst[e0 + i] >> 8], 1);
    __syncthreads();
    for (int b = tid; b < nb2; b += 256)
      if (lh[b]) atomicAdd(&bcnt[b], lh[b]);
  }
}

__global__ __launch_bounds__(512) void k_bscan(
    const int* __restrict__ bcnt, int* __restrict__ bbase, int* __restrict__ bcur,
    int* __restrict__ row_start, int E, int N, int nb2) {
  __shared__ int ts[512];
  int tid = threadIdx.x;
  int v = (tid < nb2) ? bcnt[tid] : 0;
  ts[tid] = v;
  __syncthreads();
  for (int off = 1; off < 512; off <<= 1) {
    int t = (tid >= off) ? ts[tid - off] : 0;
    __syncthreads();
    ts[tid] += t;
    __syncthreads();
  }
  if (tid < nb2) { bbase[tid] = ts[tid] - v; bcur[tid] = ts[tid] - v; }
  if (tid == 0) { bbase[nb2] = E; row_start[N] = E; }
}

// partition edges into per-bucket regions of ebuf (bucket = dst>>8).
// ebuf entry packed: (src << 8) | (dst & 255) -- 4 B/edge.
__global__ __launch_bounds__(256) void k_part(
    const int* __restrict__ src, const int* __restrict__ dst,
    int* __restrict__ bcur, unsigned int* __restrict__ ebuf, int E, int nb2) {
  __shared__ int lh[MAXB];
  int tid = threadIdx.x;
  int e0 = blockIdx.x * PB;
  for (int b = tid; b < nb2; b += 256) lh[b] = 0;
  __syncthreads();
  int cnt = min(PB, E - e0);
  for (int i = tid; i < cnt; i += 256) atomicAdd(&lh[dst[e0 + i] >> 8], 1);
  __syncthreads();
  for (int b = tid; b < nb2; b += 256) {
    int c = lh[b];
    lh[b] = (c > 0) ? atomicAdd(&bcur[b], c) : 0;
  }
  __syncthreads();
  for (int i = tid; i < cnt; i += 256) {
    int s = src[e0 + i];
    int d = dst[e0 + i];
    int pos = atomicAdd(&lh[d >> 8], 1);
    ebuf[pos] = ((unsigned)s << 8) | ((unsigned)d & 255u);
  }
}

// one block per bucket: LDS count + scan -> row_start; LDS cursors -> csr.
__global__ __launch_bounds__(256) void k_fill2(
    const unsigned int* __restrict__ ebuf, const int* __restrict__ bbase,
    int* __restrict__ row_start, int* __restrict__ csr, int N) {
  __shared__ int lcnt[256];
  __shared__ int lcur[256];
  __shared__ int ts[256];
  int b = blockIdx.x;
  int tid = threadIdx.x;
  int start = bbase[b], end = bbase[b + 1];
  lcnt[tid] = 0;
  __syncthreads();
  for (int i = start + tid; i < end; i += 256)
    atomicAdd(&lcnt[ebuf[i] & 255u], 1);
  __syncthreads();
  int v = lcnt[tid];
  ts[tid] = v;
  __syncthreads();
  for (int off = 1; off < 256; off <<= 1) {
    int t = (tid >= off) ? ts[tid - off] : 0;
    __syncthreads();
    ts[tid] += t;
    __syncthreads();
  }
  int excl = start + ts[tid] - v;
  int node = (b << 8) + tid;
  if (node < N) row_start[node] = excl;
  lcur[tid] = excl;
  __syncthreads();
  for (int i = start + tid; i < end; i += 256) {
    unsigned int e = ebuf[i];
    int pos = atomicAdd(&lcur[e & 255u], 1);
    csr[pos] = (int)(e >> 8);
  }
}

// ---------------------------------------------------------------------------
// k_agg: one wave per node; quarter-wave (16 lanes) per edge row, uint4
// (16 B) gathers -- half the index loads / gathers / address VALU of the
// 8 B variant. fp32 packed accumulate; quarters combined via 2 shfl rounds;
// fp8 mean written row-major by lanes 0..15 (16 x 16 B = 256 B).
// ---------------------------------------------------------------------------
__global__ __launch_bounds__(256) void k_agg(
    const uint4* __restrict__ xq4, const int* __restrict__ csr,
    const int* __restrict__ row_start, uint4* __restrict__ aggrm, int N) {
  int wid = (int)((blockIdx.x * (unsigned)blockDim.x + threadIdx.x) >> 6);
  int lane = threadIdx.x & 63;
  int q = lane >> 4;          // edge slot 0..3
  int l16 = lane & 15;
  if (wid >= N) return;
  int start = row_start[wid];
  int end = row_start[wid + 1];
  int c = end - start;
  floatx2 a[8], b[8];
#pragma unroll
  for (int j = 0; j < 8; j++) {
    a[j] = (floatx2){0.f, 0.f};
    b[j] = (floatx2){0.f, 0.f};
  }
  int i = 0;
  for (; i + 8 <= c; i += 8) {
    int s0 = csr[start + i + q];
    int s1 = csr[start + i + 4 + q];
    uint4 v0 = xq4[(size_t)s0 * 16 + l16];
    uint4 v1 = xq4[(size_t)s1 * 16 + l16];
    acc16p(v0, a);
    acc16p(v1, b);
  }
  for (; i < c; i += 4) {
    int idx = i + q;
    if (idx < c) {
      int s0 = csr[start + idx];
      uint4 v0 = xq4[(size_t)s0 * 16 + l16];
      acc16p(v0, a);
    }
  }
#pragma unroll
  for (int j = 0; j < 8; j++) a[j] += b[j];

  float f[16];
#pragma unroll
  for (int j = 0; j < 8; j++) { f[2 * j] = a[j].x; f[2 * j + 1] = a[j].y; }
#pragma unroll
  for (int j = 0; j < 16; j++) {
    f[j] += __shfl_xor(f[j], 16);
    f[j] += __shfl_xor(f[j], 32);
  }

  if (q == 0) {
    float inv = 1.0f / fmaxf((float)c, 1.0f);
#pragma unroll
    for (int j = 0; j < 16; j++) f[j] *= inv;
    unsigned wds[4];
#pragma unroll
    for (int j = 0; j < 4; j++) {
      int lo = __builtin_amdgcn_cvt_pk_fp8_f32(f[4 * j], f[4 * j + 1], 0, false);
      wds[j] = (unsigned)__builtin_amdgcn_cvt_pk_fp8_f32(
          f[4 * j + 2], f[4 * j + 3], lo, true);
    }
    aggrm[(size_t)wid * 16 + l16] = make_uint4(wds[0], wds[1], wds[2], wds[3]);
  }
}

// ---------------------------------------------------------------------------
// k_tr: transpose row-major agg -> fragment-linear Aqagg. 64 nodes/block;
// coalesced read & write through LDS (node stride 33 uint2 -> 2-way banks).
// ---------------------------------------------------------------------------
__global__ __launch_bounds__(256) void k_tr(
    const uint2* __restrict__ rm, uint2* __restrict__ fr, int N) {
  __shared__ uint2 ld[64 * 33];
  int b = blockIdx.x;
  int tid = threadIdx.x;
  int n0 = b * 64;
#pragma unroll
  for (int j = 0; j < 8; j++) {
    int idx = j * 256 + tid;       // 0..2047
    int nl = idx >> 5, u = idx & 31;
    int node = n0 + nl;
    uint2 v = (node < N) ? rm[(size_t)node * 32 + u] : make_uint2(0u, 0u);
    ld[nl * 33 + u] = v;
  }
  __syncthreads();
  size_t obase = (size_t)b * 2048;   // 2 groups x 1024 uint2
#pragma unroll
  for (int j = 0; j < 8; j++) {
    int oidx = j * 256 + tid;      // 0..2047
    int gg = oidx >> 10, rem = oidx & 1023;
    int c = rem >> 6, hr = rem & 63, hi = hr >> 5, row = hr & 31;
    int nl = gg * 32 + row, u = c * 2 + hi;
    fr[obase + oidx] = ld[nl * 33 + u];
  }
}

// ---------------------------------------------------------------------------
// k_h: block 128 rows x 128 cols (gridDim.y = col half), 4 waves 2x2, wave
// tile 64x64 (acc = 64 regs). BK=64, 8 chunks, LDS double-buffered, one
// barrier per chunk; global_load_lds 1 KB wave-DMAs from fragment-linear
// fp8 A / bf16 B; lane-linear LDS consumes (2-way banks = free).
// Epilogue: per-block colsum partials stored PLAIN (no global atomics).
// C/D: col=lane&31, row=(reg&3)+8*(reg>>2)+4*(lane>>5)  [m74/m101 verified]
// ---------------------------------------------------------------------------
__global__ __launch_bounds__(256, 3) void k_h(
    const unsigned char* __restrict__ Aqx, const unsigned char* __restrict__ Aqagg,
    const unsigned char* __restrict__ Bf8, const float* __restrict__ bself,
    const float* __restrict__ bnei, float* __restrict__ hpart, int N) {
  __shared__ __align__(16) unsigned char As[2][8192];    // 16 KB
  __shared__ __align__(16) unsigned char Bs[2][16384];   // 32 KB
  __shared__ float colsum[128];
  int tid = threadIdx.x;
  int lane = tid & 63;
  int w = tid >> 6;
  int wr = w >> 1, wc = w & 1;
  int l32 = lane & 31, half = lane >> 5;
  int bx = blockIdx.x, by = blockIdx.y;
  int rowBase = bx * 128;

  if (tid < 128) colsum[tid] = 0.f;

  floatx16 acc[2][2];
#pragma unroll
  for (int i = 0; i < 2; i++)
#pragma unroll
    for (int j = 0; j < 2; j++) acc[i][j] = (floatx16)(0.f);

  size_t a_grp = (size_t)(bx * 4 + w) * 16 * 512;
  int lb = lane * 16;

  // prologue: stage chunk 0
  {
    const unsigned char* asrc = Aqx + a_grp + lb;
    gl16(asrc, As[0] + w * 2048);
    gl16(asrc + 1024, As[0] + w * 2048 + 1024);
#pragma unroll
    for (int fi = 0; fi < 4; fi++) {
      int ctg = by * 4 + fi;
      gl16(Bf8 + (size_t)(w * 8 + ctg) * 1024 + lb, Bs[0] + (w * 4 + fi) * 1024);
    }
  }

  for (int ch = 0; ch < 8; ch++) {
    int buf = ch & 1;
    __syncthreads();
    if (ch < 7) {
      int cn = ch + 1;
      const unsigned char* Aq = (cn < 4) ? Aqx : Aqagg;
      const unsigned char* asrc = Aq + a_grp + (size_t)(cn & 3) * 2048 + lb;
      unsigned char* ad = As[buf ^ 1] + w * 2048;
      gl16(asrc, ad);
      gl16(asrc + 1024, ad + 1024);
#pragma unroll
      for (int fi = 0; fi < 4; fi++) {
        int cg = cn * 4 + w;
        int ctg = by * 4 + fi;
        gl16(Bf8 + (size_t)(cg * 8 + ctg) * 1024 + lb,
             Bs[buf ^ 1] + (w * 4 + fi) * 1024);
      }
    }
#pragma unroll
    for (int cl = 0; cl < 4; cl++) {
      short8 afr[2];
#pragma unroll
      for (int rt = 0; rt < 2; rt++) {
        uint2 av = *(const uint2*)&As[buf][(wr * 2 + rt) * 2048 + cl * 512 + lane * 8];
        afr[rt] = dec8(av);
      }
#pragma unroll
      for (int ctw = 0; ctw < 2; ctw++) {
        short8 bfr = *(const short8*)&Bs[buf][(cl * 4 + wc * 2 + ctw) * 1024 + lane * 16];
#pragma unroll
        for (int rt = 0; rt < 2; rt++)
          acc[rt][ctw] = __builtin_amdgcn_mfma_f32_32x32x16_bf16(
              afr[rt], bfr, acc[rt][ctw], 0, 0, 0);
      }
    }
  }

  // epilogue: bias + relu + row-masked column sums -> plain partial store
#pragma unroll
  for (int ctw = 0; ctw < 2; ctw++) {
    int lcol = (wc * 2 + ctw) * 32 + l32;
    int gcol = by * 128 + lcol;
    float bb = bself[gcol] + bnei[gcol];
    float psum = 0.f;
#pragma unroll
    for (int rt = 0; rt < 2; rt++) {
#pragma unroll
      for (int r = 0; r < 16; r++) {
        int rw = rowBase + wr * 64 + rt * 32 + (r & 3) + 8 * (r >> 2) + 4 * half;
        float v = acc[rt][ctw][r] + bb;
        v = v > 0.f ? v : 0.f;
        if (rw < N) psum += v;
      }
    }
    atomicAdd(&colsum[lcol], psum);   // LDS only (2 adds/col)
  }
  __syncthreads();
  if (tid < 128) hpart[(size_t)bx * 256 + by * 128 + tid] = colsum[tid];
}

// ---------------------------------------------------------------------------
// k_red: parallel reduction of hpart rows -> gsum. Coalesced 1 KB row reads,
// grid-stride; one global atomic per (block, column).
// ---------------------------------------------------------------------------
__global__ __launch_bounds__(256) void k_red(
    const float* __restrict__ hpart, float* __restrict__ gsum, int nbx) {
  int c = threadIdx.x;
  float s = 0.f;
  for (int i = blockIdx.x; i < nbx; i += gridDim.x)
    s += hpart[(size_t)i * 256 + c];
  atomicAdd(&gsum[c], s);
}

// ---------------------------------------------------------------------------
// k_out: out = (gsum / N) @ W_out + b_out   single block, 256 threads
// ---------------------------------------------------------------------------
__global__ __launch_bounds__(HID) void k_out(
    const float* __restrict__ gsum, const float* __restrict__ Wout,
    const float* __restrict__ bout, float* __restrict__ out, float invN) {
  __shared__ float g[HID];
  int c = threadIdx.x;
  g[c] = gsum[c] * invN;
  __syncthreads();
  float acc = bout[c];
#pragma unroll 8
  for (int k = 0; k < HID; k++) acc += g[k] * Wout[k * HID + c];
  out[c] = acc;
}

extern "C" void kernel_launch(void* const* d_in, const int* in_sizes, int n_in,
                              void* d_out, int out_size, void* d_ws, size_t ws_size,
                              hipStream_t stream) {
  const float* ns    = (const float*)d_in[0];
  const float* Win   = (const float*)d_in[1];
  const float* bin   = (const float*)d_in[2];
  const float* Wself = (const float*)d_in[3];
  const float* bself = (const float*)d_in[4];
  const float* Wnei  = (const float*)d_in[5];
  const float* bnei  = (const float*)d_in[6];
  const float* Wout  = (const float*)d_in[7];
  const float* bout  = (const float*)d_in[8];
  const int*   eidx  = (const int*)d_in[9];

  int N = in_sizes[0] / IND;
  int E = in_sizes[9] / 2;
  const int* src = eidx;
  const int* dst = eidx + E;
  int nb2 = (N + 255) >> 8;
  int nbx = (N + 127) / 128;                 // k_h row-tiles
  size_t NGU = (size_t)nbx * 4 * 16 * 64;    // fragment uint2 count (padded)

  // ws: xq | Aqx | Aqagg | aggrm | Bf16 | csr | ebuf | row_start | bcnt |
  //     bbase | bcur | gsum | hpart
  unsigned int* xq     = (unsigned int*)d_ws;
  uint2* Aqx           = (uint2*)(xq + (size_t)N * 64);
  uint2* Aqagg         = Aqx + NGU;
  uint2* aggrm         = Aqagg + NGU;
  unsigned short* Bf16 = (unsigned short*)(aggrm + (size_t)N * 32);
  int* csr       = (int*)(Bf16 + 256 * 512);
  unsigned int* ebuf = (unsigned int*)(csr + E);
  int* row_start = (int*)(ebuf + E);
  int* bcnt      = row_start + N + 1;
  int* bbase     = bcnt + MAXB;
  int* bcur      = bbase + MAXB + 1;
  float* gsum    = (float*)(bcur + MAXB);
  float* hpart   = gsum + HID;

  hipMemsetAsync(bcnt, 0, MAXB * sizeof(int), stream);
  hipMemsetAsync(gsum, 0, HID * sizeof(float), stream);

  int G1 = (N + 7) / 8;
  int pgrid = (E + PB - 1) / PB;
  k_front<<<G1 + 256 + pgrid, 256, 0, stream>>>(
      ns, Win, bin, (uint2*)xq, Aqx, Wself, Wnei, Bf16, dst, bcnt,
      N, E, nb2, G1);

  k_bscan<<<1, 512, 0, stream>>>(bcnt, bbase, bcur, row_start, E, N, nb2);
  k_part<<<pgrid, 256, 0, stream>>>(src, dst, bcur, ebuf, E, nb2);
  k_fill2<<<nb2, 256, 0, stream>>>(ebuf, bbase, row_start, csr, N);

  int agrid = (N + 3) / 4;
  k_agg<<<agrid, 256, 0, stream>>>((const uint4*)xq, csr, row_start,
                                   (uint4*)aggrm, N);

  int tgrid = (N + 63) / 64;
  k_tr<<<tgrid, 256, 0, stream>>>(aggrm, Aqagg, N);

  dim3 hgrid(nbx, 2);
  k_h<<<hgrid, 256, 0, stream>>>((const unsigned char*)Aqx,
                                 (const unsigned char*)Aqagg,
                                 (const unsigned char*)Bf16,
                                 bself, bnei, hpart, N);

  k_red<<<64, 256, 0, stream>>>(hpart, gsum, nbx);
  k_out<<<1, HID, 0, stream>>>(gsum, Wout, bout, (float*)d_out, 1.0f / (float)N);
}

// Round 17
// 301.210 us; speedup vs baseline: 1.6020x; 1.0297x over previous
//
#include <hip/hip_runtime.h>
#include <hip/hip_bf16.h>

#define HID 256
#define IND 21
#define PB 6400      // edges per block in k_part / bhist
#define MAXB 512     // max buckets (N <= 131072)

typedef short short8 __attribute__((ext_vector_type(8)));
typedef float floatx16 __attribute__((ext_vector_type(16)));
typedef float floatx2 __attribute__((ext_vector_type(2)));

__device__ inline unsigned short f2bf(float f) {
  __hip_bfloat16 h = __float2bfloat16(f);  // RNE
  union { __hip_bfloat16 h; unsigned short u; } c;
  c.h = h;
  return c.u;
}

// pack float2 -> 2 bf16 by truncation (exact for values that came from fp8)
__device__ inline unsigned int pk_bf16_trunc(floatx2 p) {
  union { float f; unsigned int u; } a, b;
  a.f = p.x; b.f = p.y;
  return (b.u & 0xffff0000u) | (a.u >> 16);
}

// accumulate 8 fp8 bytes into 4 packed-f32 accumulators
__device__ inline void acc8p(uint2 v, floatx2* a) {
  a[0] += __builtin_amdgcn_cvt_pk_f32_fp8((int)v.x, false);
  a[1] += __builtin_amdgcn_cvt_pk_f32_fp8((int)v.x, true);
  a[2] += __builtin_amdgcn_cvt_pk_f32_fp8((int)v.y, false);
  a[3] += __builtin_amdgcn_cvt_pk_f32_fp8((int)v.y, true);
}

__device__ inline short8 mk_s8(unsigned a, unsigned b, unsigned c, unsigned d) {
  union { uint4 u; short8 s; } x; x.u = make_uint4(a, b, c, d); return x.s;
}

// decode 8 fp8 bytes (uint2) -> short8 of bf16 (exact)
__device__ inline short8 dec8(uint2 v) {
  unsigned w0 = pk_bf16_trunc(__builtin_amdgcn_cvt_pk_f32_fp8((int)v.x, false));
  unsigned w1 = pk_bf16_trunc(__builtin_amdgcn_cvt_pk_f32_fp8((int)v.x, true));
  unsigned w2 = pk_bf16_trunc(__builtin_amdgcn_cvt_pk_f32_fp8((int)v.y, false));
  unsigned w3 = pk_bf16_trunc(__builtin_amdgcn_cvt_pk_f32_fp8((int)v.y, true));
  return mk_s8(w0, w1, w2, w3);
}

// async global->LDS DMA, 16 B/lane. LDS dest = (uniform) base + lane*16.
__device__ inline void gl16(const unsigned char* g, unsigned char* l) {
  __builtin_amdgcn_global_load_lds(
      (const __attribute__((address_space(1))) unsigned char*)g,
      (__attribute__((address_space(3))) unsigned char*)l, 16, 0, 0);
}

// ---------------------------------------------------------------------------
// fused front kernel: [0,G1) linear_in | [G1,G1+256) wconv | rest bhist
// linear_in pack phase: thread = (node j = tid&7, unit u = tid>>3) -> LDS
// reads 2-way-bank-free; one uint2 pack serves BOTH row-major xq and
// fragment-linear Aqx with 64 B-dense wave writes.
// wconv writes B fragment-linear:
//   Bf16[((c*8+ct)*64 + lane)*8 + j] = W[c*16+(lane>>5)*8+j][ct*32+(lane&31)]
// ---------------------------------------------------------------------------
__global__ __launch_bounds__(256) void k_front(
    const float* __restrict__ ns, const float* __restrict__ Win,
    const float* __restrict__ bin, uint2* __restrict__ xq2,
    uint2* __restrict__ Aqx,
    const float* __restrict__ Wself, const float* __restrict__ Wnei,
    unsigned short* __restrict__ Bf16,
    const int* __restrict__ dst, int* __restrict__ bcnt,
    int N, int E, int nb2, int G1) {
  int blk = blockIdx.x;
  int tid = threadIdx.x;
  if (blk < G1) {
    __shared__ float s[8][IND];
    __shared__ float fx[8][257];
    int nb = blk * 8;
    if (tid < 8 * IND) {
      int idx = nb * IND + tid;
      s[tid / IND][tid % IND] = (idx < N * IND) ? ns[idx] : 0.f;
    }
    float w[IND];
#pragma unroll
    for (int k = 0; k < IND; k++) w[k] = Win[k * HID + tid];
    float b = bin[tid];
    __syncthreads();
#pragma unroll
    for (int j = 0; j < 8; j++) {
      float acc = b;
#pragma unroll
      for (int k = 0; k < IND; k++) acc += s[j][k] * w[k];
      fx[j][tid] = acc > 0.f ? acc : 0.f;
    }
    __syncthreads();
    // pack: one uint2 (8 fp8) per thread -> xq (row-major) + Aqx (fragment)
    {
      int j = tid & 7, u = tid >> 3;    // node-local, 8-col unit 0..31
      int node = nb + j;
      if (node < N) {
        const float* fp = &fx[j][u * 8];
        int lo0 = __builtin_amdgcn_cvt_pk_fp8_f32(fp[0], fp[1], 0, false);
        int w0  = __builtin_amdgcn_cvt_pk_fp8_f32(fp[2], fp[3], lo0, true);
        int lo1 = __builtin_amdgcn_cvt_pk_fp8_f32(fp[4], fp[5], 0, false);
        int w1  = __builtin_amdgcn_cvt_pk_fp8_f32(fp[6], fp[7], lo1, true);
        uint2 val = make_uint2((unsigned)w0, (unsigned)w1);
        xq2[(size_t)node * 32 + u] = val;
        int g = node >> 5, row = node & 31, c = u >> 1, hi = u & 1;
        Aqx[(size_t)(g * 16 + c) * 64 + hi * 32 + row] = val;
      }
    }
  } else if (blk < G1 + 256) {
    int n = blk - G1;           // output column 0..255
    int ct = n >> 5, l5 = n & 31;
#pragma unroll
    for (int t = 0; t < 2; t++) {
      int k = tid + t * 256;    // 0..511
      float v = (k < HID) ? Wself[k * HID + n] : Wnei[(k - HID) * HID + n];
      int c = k >> 4, kin = k & 15;
      int lane = (kin >> 3) * 32 + l5;
      int j = kin & 7;
      Bf16[(size_t)((c * 8 + ct) * 64 + lane) * 8 + j] = f2bf(v);
    }
  } else {
    __shared__ int lh[MAXB];
    int e0 = (blk - G1 - 256) * PB;
    for (int b = tid; b < nb2; b += 256) lh[b] = 0;
    __syncthreads();
    int c = min(PB, E - e0);
    for (int i = tid; i < c; i += 256) atomicAdd(&lh[dst[e0 + i] >> 8], 1);
    __syncthreads();
    for (int b = tid; b < nb2; b += 256)
      if (lh[b]) atomicAdd(&bcnt[b], lh[b]);
  }
}

__global__ __launch_bounds__(512) void k_bscan(
    const int* __restrict__ bcnt, int* __restrict__ bbase, int* __restrict__ bcur,
    int* __restrict__ row_start, int E, int N, int nb2) {
  __shared__ int ts[512];
  int tid = threadIdx.x;
  int v = (tid < nb2) ? bcnt[tid] : 0;
  ts[tid] = v;
  __syncthreads();
  for (int off = 1; off < 512; off <<= 1) {
    int t = (tid >= off) ? ts[tid - off] : 0;
    __syncthreads();
    ts[tid] += t;
    __syncthreads();
  }
  if (tid < nb2) { bbase[tid] = ts[tid] - v; bcur[tid] = ts[tid] - v; }
  if (tid == 0) { bbase[nb2] = E; row_start[N] = E; }
}

// partition edges into per-bucket regions of ebuf (bucket = dst>>8).
// ebuf entry packed: (src << 8) | (dst & 255) -- 4 B/edge.
__global__ __launch_bounds__(256) void k_part(
    const int* __restrict__ src, const int* __restrict__ dst,
    int* __restrict__ bcur, unsigned int* __restrict__ ebuf, int E, int nb2) {
  __shared__ int lh[MAXB];
  int tid = threadIdx.x;
  int e0 = blockIdx.x * PB;
  for (int b = tid; b < nb2; b += 256) lh[b] = 0;
  __syncthreads();
  int cnt = min(PB, E - e0);
  for (int i = tid; i < cnt; i += 256) atomicAdd(&lh[dst[e0 + i] >> 8], 1);
  __syncthreads();
  for (int b = tid; b < nb2; b += 256) {
    int c = lh[b];
    lh[b] = (c > 0) ? atomicAdd(&bcur[b], c) : 0;
  }
  __syncthreads();
  for (int i = tid; i < cnt; i += 256) {
    int s = src[e0 + i];
    int d = dst[e0 + i];
    int pos = atomicAdd(&lh[d >> 8], 1);
    ebuf[pos] = ((unsigned)s << 8) | ((unsigned)d & 255u);
  }
}

// one block per bucket: LDS count + scan -> row_start; LDS cursors -> csr.
// csr stores the BYTE OFFSET of the source row (src*256 == e & ~255).
__global__ __launch_bounds__(256) void k_fill2(
    const unsigned int* __restrict__ ebuf, const int* __restrict__ bbase,
    int* __restrict__ row_start, unsigned int* __restrict__ csr, int N) {
  __shared__ int lcnt[256];
  __shared__ int lcur[256];
  __shared__ int ts[256];
  int b = blockIdx.x;
  int tid = threadIdx.x;
  int start = bbase[b], end = bbase[b + 1];
  lcnt[tid] = 0;
  __syncthreads();
  for (int i = start + tid; i < end; i += 256)
    atomicAdd(&lcnt[ebuf[i] & 255u], 1);
  __syncthreads();
  int v = lcnt[tid];
  ts[tid] = v;
  __syncthreads();
  for (int off = 1; off < 256; off <<= 1) {
    int t = (tid >= off) ? ts[tid - off] : 0;
    __syncthreads();
    ts[tid] += t;
    __syncthreads();
  }
  int excl = start + ts[tid] - v;
  int node = (b << 8) + tid;
  if (node < N) row_start[node] = excl;
  lcur[tid] = excl;
  __syncthreads();
  for (int i = start + tid; i < end; i += 256) {
    unsigned int e = ebuf[i];
    int pos = atomicAdd(&lcur[e & 255u], 1);
    csr[pos] = e & ~255u;   // byte offset of source row (src * 256)
  }
}

// ---------------------------------------------------------------------------
// k_agg: one wave per node; 2 edges per iteration (each 32-lane half gathers
// one 256 B row at 8 B/lane), 8 edges unrolled (4 loads in flight per half).
// csr holds byte offsets -> gather address is a single 32-bit add feeding
// saddr-form global_load. fp32 packed accumulate; halves combined via
// shfl_xor(32); fp8 mean written dense row-major by the lower half.
// ---------------------------------------------------------------------------
__global__ __launch_bounds__(256) void k_agg(
    const unsigned char* __restrict__ xqb, const unsigned int* __restrict__ csrb,
    const int* __restrict__ row_start, uint2* __restrict__ aggrm, int N) {
  int wid = (int)((blockIdx.x * (unsigned)blockDim.x + threadIdx.x) >> 6);
  int lane = threadIdx.x & 63;
  int half = lane >> 5;
  int l32 = lane & 31;
  if (wid >= N) return;
  int start = row_start[wid];
  int end = row_start[wid + 1];
  int c = end - start;
  unsigned lo = (unsigned)(l32 * 8);
  floatx2 a[4], b[4], d[4], e[4];
#pragma unroll
  for (int j = 0; j < 4; j++) {
    a[j] = (floatx2){0.f, 0.f}; b[j] = (floatx2){0.f, 0.f};
    d[j] = (floatx2){0.f, 0.f}; e[j] = (floatx2){0.f, 0.f};
  }
  int i = 0;
  for (; i + 8 <= c; i += 8) {
    unsigned o0 = csrb[start + i + half] + lo;
    unsigned o1 = csrb[start + i + 2 + half] + lo;
    unsigned o2 = csrb[start + i + 4 + half] + lo;
    unsigned o3 = csrb[start + i + 6 + half] + lo;
    uint2 v0 = *(const uint2*)(xqb + o0);
    uint2 v1 = *(const uint2*)(xqb + o1);
    uint2 v2 = *(const uint2*)(xqb + o2);
    uint2 v3 = *(const uint2*)(xqb + o3);
    acc8p(v0, a); acc8p(v1, b); acc8p(v2, d); acc8p(v3, e);
  }
  for (; i + 2 <= c; i += 2) {
    unsigned o0 = csrb[start + i + half] + lo;
    uint2 v0 = *(const uint2*)(xqb + o0);
    acc8p(v0, a);
  }
  if ((c & 1) && half == 0) {
    unsigned o0 = csrb[start + c - 1] + lo;
    uint2 v0 = *(const uint2*)(xqb + o0);
    acc8p(v0, a);
  }
#pragma unroll
  for (int j = 0; j < 4; j++) a[j] += b[j] + d[j] + e[j];

  float f[8];
#pragma unroll
  for (int j = 0; j < 4; j++) { f[2 * j] = a[j].x; f[2 * j + 1] = a[j].y; }
#pragma unroll
  for (int j = 0; j < 8; j++) f[j] += __shfl_xor(f[j], 32);

  if (half == 0) {
    float inv = 1.0f / fmaxf((float)c, 1.0f);
#pragma unroll
    for (int j = 0; j < 8; j++) f[j] *= inv;
    int lo0 = __builtin_amdgcn_cvt_pk_fp8_f32(f[0], f[1], 0, false);
    int w0  = __builtin_amdgcn_cvt_pk_fp8_f32(f[2], f[3], lo0, true);
    int lo1 = __builtin_amdgcn_cvt_pk_fp8_f32(f[4], f[5], 0, false);
    int w1  = __builtin_amdgcn_cvt_pk_fp8_f32(f[6], f[7], lo1, true);
    aggrm[(size_t)wid * 32 + l32] = make_uint2((unsigned)w0, (unsigned)w1);
  }
}

// ---------------------------------------------------------------------------
// k_tr: transpose row-major agg -> fragment-linear Aqagg. 64 nodes/block;
// coalesced read & write through LDS (node stride 33 uint2 -> 2-way banks).
// ---------------------------------------------------------------------------
__global__ __launch_bounds__(256) void k_tr(
    const uint2* __restrict__ rm, uint2* __restrict__ fr, int N) {
  __shared__ uint2 ld[64 * 33];
  int b = blockIdx.x;
  int tid = threadIdx.x;
  int n0 = b * 64;
#pragma unroll
  for (int j = 0; j < 8; j++) {
    int idx = j * 256 + tid;       // 0..2047
    int nl = idx >> 5, u = idx & 31;
    int node = n0 + nl;
    uint2 v = (node < N) ? rm[(size_t)node * 32 + u] : make_uint2(0u, 0u);
    ld[nl * 33 + u] = v;
  }
  __syncthreads();
  size_t obase = (size_t)b * 2048;   // 2 groups x 1024 uint2
#pragma unroll
  for (int j = 0; j < 8; j++) {
    int oidx = j * 256 + tid;      // 0..2047
    int gg = oidx >> 10, rem = oidx & 1023;
    int c = rem >> 6, hr = rem & 63, hi = hr >> 5, row = hr & 31;
    int nl = gg * 32 + row, u = c * 2 + hi;
    fr[obase + oidx] = ld[nl * 33 + u];
  }
}

// ---------------------------------------------------------------------------
// k_h: block 128 rows x 128 cols (gridDim.y = col half), 4 waves 2x2, wave
// tile 64x64 (acc = 64 regs). BK=64, 8 chunks, LDS double-buffered, one
// barrier per chunk; global_load_lds 1 KB wave-DMAs from fragment-linear
// fp8 A / bf16 B; lane-linear LDS consumes (2-way banks = free).
// Epilogue: per-block colsum partials stored PLAIN (no global atomics).
// C/D: col=lane&31, row=(reg&3)+8*(reg>>2)+4*(lane>>5)  [m74/m101 verified]
// ---------------------------------------------------------------------------
__global__ __launch_bounds__(256, 3) void k_h(
    const unsigned char* __restrict__ Aqx, const unsigned char* __restrict__ Aqagg,
    const unsigned char* __restrict__ Bf8, const float* __restrict__ bself,
    const float* __restrict__ bnei, float* __restrict__ hpart, int N) {
  __shared__ __align__(16) unsigned char As[2][8192];    // 16 KB
  __shared__ __align__(16) unsigned char Bs[2][16384];   // 32 KB
  __shared__ float colsum[128];
  int tid = threadIdx.x;
  int lane = tid & 63;
  int w = tid >> 6;
  int wr = w >> 1, wc = w & 1;
  int l32 = lane & 31, half = lane >> 5;
  int bx = blockIdx.x, by = blockIdx.y;
  int rowBase = bx * 128;

  if (tid < 128) colsum[tid] = 0.f;

  floatx16 acc[2][2];
#pragma unroll
  for (int i = 0; i < 2; i++)
#pragma unroll
    for (int j = 0; j < 2; j++) acc[i][j] = (floatx16)(0.f);

  size_t a_grp = (size_t)(bx * 4 + w) * 16 * 512;
  int lb = lane * 16;

  // prologue: stage chunk 0
  {
    const unsigned char* asrc = Aqx + a_grp + lb;
    gl16(asrc, As[0] + w * 2048);
    gl16(asrc + 1024, As[0] + w * 2048 + 1024);
#pragma unroll
    for (int fi = 0; fi < 4; fi++) {
      int ctg = by * 4 + fi;
      gl16(Bf8 + (size_t)(w * 8 + ctg) * 1024 + lb, Bs[0] + (w * 4 + fi) * 1024);
    }
  }

  for (int ch = 0; ch < 8; ch++) {
    int buf = ch & 1;
    __syncthreads();
    if (ch < 7) {
      int cn = ch + 1;
      const unsigned char* Aq = (cn < 4) ? Aqx : Aqagg;
      const unsigned char* asrc = Aq + a_grp + (size_t)(cn & 3) * 2048 + lb;
      unsigned char* ad = As[buf ^ 1] + w * 2048;
      gl16(asrc, ad);
      gl16(asrc + 1024, ad + 1024);
#pragma unroll
      for (int fi = 0; fi < 4; fi++) {
        int cg = cn * 4 + w;
        int ctg = by * 4 + fi;
        gl16(Bf8 + (size_t)(cg * 8 + ctg) * 1024 + lb,
             Bs[buf ^ 1] + (w * 4 + fi) * 1024);
      }
    }
#pragma unroll
    for (int cl = 0; cl < 4; cl++) {
      short8 afr[2];
#pragma unroll
      for (int rt = 0; rt < 2; rt++) {
        uint2 av = *(const uint2*)&As[buf][(wr * 2 + rt) * 2048 + cl * 512 + lane * 8];
        afr[rt] = dec8(av);
      }
#pragma unroll
      for (int ctw = 0; ctw < 2; ctw++) {
        short8 bfr = *(const short8*)&Bs[buf][(cl * 4 + wc * 2 + ctw) * 1024 + lane * 16];
#pragma unroll
        for (int rt = 0; rt < 2; rt++)
          acc[rt][ctw] = __builtin_amdgcn_mfma_f32_32x32x16_bf16(
              afr[rt], bfr, acc[rt][ctw], 0, 0, 0);
      }
    }
  }

  // epilogue: bias + relu + row-masked column sums -> plain partial store
#pragma unroll
  for (int ctw = 0; ctw < 2; ctw++) {
    int lcol = (wc * 2 + ctw) * 32 + l32;
    int gcol = by * 128 + lcol;
    float bb = bself[gcol] + bnei[gcol];
    float psum = 0.f;
#pragma unroll
    for (int rt = 0; rt < 2; rt++) {
#pragma unroll
      for (int r = 0; r < 16; r++) {
        int rw = rowBase + wr * 64 + rt * 32 + (r & 3) + 8 * (r >> 2) + 4 * half;
        float v = acc[rt][ctw][r] + bb;
        v = v > 0.f ? v : 0.f;
        if (rw < N) psum += v;
      }
    }
    atomicAdd(&colsum[lcol], psum);   // LDS only (2 adds/col)
  }
  __syncthreads();
  if (tid < 128) hpart[(size_t)bx * 256 + by * 128 + tid] = colsum[tid];
}

// ---------------------------------------------------------------------------
// k_red: parallel reduction of hpart rows -> gsum. Coalesced 1 KB row reads,
// grid-stride; one global atomic per (block, column).
// ---------------------------------------------------------------------------
__global__ __launch_bounds__(256) void k_red(
    const float* __restrict__ hpart, float* __restrict__ gsum, int nbx) {
  int c = threadIdx.x;
  float s = 0.f;
  for (int i = blockIdx.x; i < nbx; i += gridDim.x)
    s += hpart[(size_t)i * 256 + c];
  atomicAdd(&gsum[c], s);
}

// ---------------------------------------------------------------------------
// k_out: out = (gsum / N) @ W_out + b_out   single block, 256 threads
// ---------------------------------------------------------------------------
__global__ __launch_bounds__(HID) void k_out(
    const float* __restrict__ gsum, const float* __restrict__ Wout,
    const float* __restrict__ bout, float* __restrict__ out, float invN) {
  __shared__ float g[HID];
  int c = threadIdx.x;
  g[c] = gsum[c] * invN;
  __syncthreads();
  float acc = bout[c];
#pragma unroll 8
  for (int k = 0; k < HID; k++) acc += g[k] * Wout[k * HID + c];
  out[c] = acc;
}

extern "C" void kernel_launch(void* const* d_in, const int* in_sizes, int n_in,
                              void* d_out, int out_size, void* d_ws, size_t ws_size,
                              hipStream_t stream) {
  const float* ns    = (const float*)d_in[0];
  const float* Win   = (const float*)d_in[1];
  const float* bin   = (const float*)d_in[2];
  const float* Wself = (const float*)d_in[3];
  const float* bself = (const float*)d_in[4];
  const float* Wnei  = (const float*)d_in[5];
  const float* bnei  = (const float*)d_in[6];
  const float* Wout  = (const float*)d_in[7];
  const float* bout  = (const float*)d_in[8];
  const int*   eidx  = (const int*)d_in[9];

  int N = in_sizes[0] / IND;
  int E = in_sizes[9] / 2;
  const int* src = eidx;
  const int* dst = eidx + E;
  int nb2 = (N + 255) >> 8;
  int nbx = (N + 127) / 128;                 // k_h row-tiles
  size_t NGU = (size_t)nbx * 4 * 16 * 64;    // fragment uint2 count (padded)

  // ws: xq | Aqx | Aqagg | aggrm | Bf16 | csr | ebuf | row_start | bcnt |
  //     bbase | bcur | gsum | hpart
  unsigned int* xq     = (unsigned int*)d_ws;
  uint2* Aqx           = (uint2*)(xq + (size_t)N * 64);
  uint2* Aqagg         = Aqx + NGU;
  uint2* aggrm         = Aqagg + NGU;
  unsigned short* Bf16 = (unsigned short*)(aggrm + (size_t)N * 32);
  unsigned int* csr  = (unsigned int*)(Bf16 + 256 * 512);
  unsigned int* ebuf = csr + E;
  int* row_start = (int*)(ebuf + E);
  int* bcnt      = row_start + N + 1;
  int* bbase     = bcnt + MAXB;
  int* bcur      = bbase + MAXB + 1;
  float* gsum    = (float*)(bcur + MAXB);
  float* hpart   = gsum + HID;

  hipMemsetAsync(bcnt, 0, MAXB * sizeof(int), stream);
  hipMemsetAsync(gsum, 0, HID * sizeof(float), stream);

  int G1 = (N + 7) / 8;
  int pgrid = (E + PB - 1) / PB;
  k_front<<<G1 + 256 + pgrid, 256, 0, stream>>>(
      ns, Win, bin, (uint2*)xq, Aqx, Wself, Wnei, Bf16, dst, bcnt,
      N, E, nb2, G1);

  k_bscan<<<1, 512, 0, stream>>>(bcnt, bbase, bcur, row_start, E, N, nb2);
  k_part<<<pgrid, 256, 0, stream>>>(src, dst, bcur, ebuf, E, nb2);
  k_fill2<<<nb2, 256, 0, stream>>>(ebuf, bbase, row_start, csr, N);

  int agrid = (N + 3) / 4;
  k_agg<<<agrid, 256, 0, stream>>>((const unsigned char*)xq, csr, row_start,
                                   aggrm, N);

  int tgrid = (N + 63) / 64;
  k_tr<<<tgrid, 256, 0, stream>>>(aggrm, Aqagg, N);

  dim3 hgrid(nbx, 2);
  k_h<<<hgrid, 256, 0, stream>>>((const unsigned char*)Aqx,
                                 (const unsigned char*)Aqagg,
                                 (const unsigned char*)Bf16,
                                 bself, bnei, hpart, N);

  k_red<<<64, 256, 0, stream>>>(hpart, gsum, nbx);
  k_out<<<1, HID, 0, stream>>>(gsum, Wout, bout, (float*)d_out, 1.0f / (float)N);
}

// Round 18
// 293.391 us; speedup vs baseline: 1.6447x; 1.0266x over previous
//
#include <hip/hip_runtime.h>
#include <hip/hip_bf16.h>

#define HID 256
#define IND 21
#define PB 6400      // edges per block in k_part / bhist
#define MAXB 512     // max buckets (N <= 131072)

typedef short short8 __attribute__((ext_vector_type(8)));
typedef float floatx16 __attribute__((ext_vector_type(16)));
typedef float floatx2 __attribute__((ext_vector_type(2)));

__device__ inline unsigned short f2bf(float f) {
  __hip_bfloat16 h = __float2bfloat16(f);  // RNE
  union { __hip_bfloat16 h; unsigned short u; } c;
  c.h = h;
  return c.u;
}

// pack float2 -> 2 bf16 by truncation (exact for values that came from fp8)
__device__ inline unsigned int pk_bf16_trunc(floatx2 p) {
  union { float f; unsigned int u; } a, b;
  a.f = p.x; b.f = p.y;
  return (b.u & 0xffff0000u) | (a.u >> 16);
}

// accumulate 8 fp8 bytes into 4 packed-f32 accumulators
__device__ inline void acc8p(uint2 v, floatx2* a) {
  a[0] += __builtin_amdgcn_cvt_pk_f32_fp8((int)v.x, false);
  a[1] += __builtin_amdgcn_cvt_pk_f32_fp8((int)v.x, true);
  a[2] += __builtin_amdgcn_cvt_pk_f32_fp8((int)v.y, false);
  a[3] += __builtin_amdgcn_cvt_pk_f32_fp8((int)v.y, true);
}

__device__ inline short8 mk_s8(unsigned a, unsigned b, unsigned c, unsigned d) {
  union { uint4 u; short8 s; } x; x.u = make_uint4(a, b, c, d); return x.s;
}

// decode 8 fp8 bytes (uint2) -> short8 of bf16 (exact)
__device__ inline short8 dec8(uint2 v) {
  unsigned w0 = pk_bf16_trunc(__builtin_amdgcn_cvt_pk_f32_fp8((int)v.x, false));
  unsigned w1 = pk_bf16_trunc(__builtin_amdgcn_cvt_pk_f32_fp8((int)v.x, true));
  unsigned w2 = pk_bf16_trunc(__builtin_amdgcn_cvt_pk_f32_fp8((int)v.y, false));
  unsigned w3 = pk_bf16_trunc(__builtin_amdgcn_cvt_pk_f32_fp8((int)v.y, true));
  return mk_s8(w0, w1, w2, w3);
}

// async global->LDS DMA, 16 B/lane. LDS dest = (uniform) base + lane*16.
__device__ inline void gl16(const unsigned char* g, unsigned char* l) {
  __builtin_amdgcn_global_load_lds(
      (const __attribute__((address_space(1))) unsigned char*)g,
      (__attribute__((address_space(3))) unsigned char*)l, 16, 0, 0);
}

// ---------------------------------------------------------------------------
// fused front kernel: [0,G1) linear_in | [G1,G1+256) wconv | rest bhist
// linear_in pack phase: thread = (node j = tid&7, unit u = tid>>3) -> LDS
// reads 2-way-bank-free; one uint2 pack serves BOTH row-major xq and
// fragment-linear Aqx with 64 B-dense wave writes.
// wconv writes B fragment-linear:
//   Bf16[((c*8+ct)*64 + lane)*8 + j] = W[c*16+(lane>>5)*8+j][ct*32+(lane&31)]
// ---------------------------------------------------------------------------
__global__ __launch_bounds__(256) void k_front(
    const float* __restrict__ ns, const float* __restrict__ Win,
    const float* __restrict__ bin, uint2* __restrict__ xq2,
    uint2* __restrict__ Aqx,
    const float* __restrict__ Wself, const float* __restrict__ Wnei,
    unsigned short* __restrict__ Bf16,
    const int* __restrict__ dst, int* __restrict__ bcnt,
    int N, int E, int nb2, int G1) {
  int blk = blockIdx.x;
  int tid = threadIdx.x;
  if (blk < G1) {
    __shared__ float s[8][IND];
    __shared__ float fx[8][257];
    int nb = blk * 8;
    if (tid < 8 * IND) {
      int idx = nb * IND + tid;
      s[tid / IND][tid % IND] = (idx < N * IND) ? ns[idx] : 0.f;
    }
    float w[IND];
#pragma unroll
    for (int k = 0; k < IND; k++) w[k] = Win[k * HID + tid];
    float b = bin[tid];
    __syncthreads();
#pragma unroll
    for (int j = 0; j < 8; j++) {
      float acc = b;
#pragma unroll
      for (int k = 0; k < IND; k++) acc += s[j][k] * w[k];
      fx[j][tid] = acc > 0.f ? acc : 0.f;
    }
    __syncthreads();
    // pack: one uint2 (8 fp8) per thread -> xq (row-major) + Aqx (fragment)
    {
      int j = tid & 7, u = tid >> 3;    // node-local, 8-col unit 0..31
      int node = nb + j;
      if (node < N) {
        const float* fp = &fx[j][u * 8];
        int lo0 = __builtin_amdgcn_cvt_pk_fp8_f32(fp[0], fp[1], 0, false);
        int w0  = __builtin_amdgcn_cvt_pk_fp8_f32(fp[2], fp[3], lo0, true);
        int lo1 = __builtin_amdgcn_cvt_pk_fp8_f32(fp[4], fp[5], 0, false);
        int w1  = __builtin_amdgcn_cvt_pk_fp8_f32(fp[6], fp[7], lo1, true);
        uint2 val = make_uint2((unsigned)w0, (unsigned)w1);
        xq2[(size_t)node * 32 + u] = val;
        int g = node >> 5, row = node & 31, c = u >> 1, hi = u & 1;
        Aqx[(size_t)(g * 16 + c) * 64 + hi * 32 + row] = val;
      }
    }
  } else if (blk < G1 + 256) {
    int n = blk - G1;           // output column 0..255
    int ct = n >> 5, l5 = n & 31;
#pragma unroll
    for (int t = 0; t < 2; t++) {
      int k = tid + t * 256;    // 0..511
      float v = (k < HID) ? Wself[k * HID + n] : Wnei[(k - HID) * HID + n];
      int c = k >> 4, kin = k & 15;
      int lane = (kin >> 3) * 32 + l5;
      int j = kin & 7;
      Bf16[(size_t)((c * 8 + ct) * 64 + lane) * 8 + j] = f2bf(v);
    }
  } else {
    __shared__ int lh[MAXB];
    int e0 = (blk - G1 - 256) * PB;
    for (int b = tid; b < nb2; b += 256) lh[b] = 0;
    __syncthreads();
    int c = min(PB, E - e0);
    for (int i = tid; i < c; i += 256) atomicAdd(&lh[dst[e0 + i] >> 8], 1);
    __syncthreads();
    for (int b = tid; b < nb2; b += 256)
      if (lh[b]) atomicAdd(&bcnt[b], lh[b]);
  }
}

__global__ __launch_bounds__(512) void k_bscan(
    const int* __restrict__ bcnt, int* __restrict__ bbase, int* __restrict__ bcur,
    int* __restrict__ row_start, int E, int N, int nb2) {
  __shared__ int ts[512];
  int tid = threadIdx.x;
  int v = (tid < nb2) ? bcnt[tid] : 0;
  ts[tid] = v;
  __syncthreads();
  for (int off = 1; off < 512; off <<= 1) {
    int t = (tid >= off) ? ts[tid - off] : 0;
    __syncthreads();
    ts[tid] += t;
    __syncthreads();
  }
  if (tid < nb2) { bbase[tid] = ts[tid] - v; bcur[tid] = ts[tid] - v; }
  if (tid == 0) { bbase[nb2] = E; row_start[N] = E; }
}

// partition edges into per-bucket regions of ebuf (bucket = dst>>8).
// ebuf entry packed: (src << 8) | (dst & 255) -- 4 B/edge.
__global__ __launch_bounds__(256) void k_part(
    const int* __restrict__ src, const int* __restrict__ dst,
    int* __restrict__ bcur, unsigned int* __restrict__ ebuf, int E, int nb2) {
  __shared__ int lh[MAXB];
  int tid = threadIdx.x;
  int e0 = blockIdx.x * PB;
  for (int b = tid; b < nb2; b += 256) lh[b] = 0;
  __syncthreads();
  int cnt = min(PB, E - e0);
  for (int i = tid; i < cnt; i += 256) atomicAdd(&lh[dst[e0 + i] >> 8], 1);
  __syncthreads();
  for (int b = tid; b < nb2; b += 256) {
    int c = lh[b];
    lh[b] = (c > 0) ? atomicAdd(&bcur[b], c) : 0;
  }
  __syncthreads();
  for (int i = tid; i < cnt; i += 256) {
    int s = src[e0 + i];
    int d = dst[e0 + i];
    int pos = atomicAdd(&lh[d >> 8], 1);
    ebuf[pos] = ((unsigned)s << 8) | ((unsigned)d & 255u);
  }
}

// one block per bucket: LDS count + scan -> row_start; LDS cursors -> csr.
// csr stores the BYTE OFFSET of the source row (src*256 == e & ~255).
__global__ __launch_bounds__(256) void k_fill2(
    const unsigned int* __restrict__ ebuf, const int* __restrict__ bbase,
    int* __restrict__ row_start, unsigned int* __restrict__ csr, int N) {
  __shared__ int lcnt[256];
  __shared__ int lcur[256];
  __shared__ int ts[256];
  int b = blockIdx.x;
  int tid = threadIdx.x;
  int start = bbase[b], end = bbase[b + 1];
  lcnt[tid] = 0;
  __syncthreads();
  for (int i = start + tid; i < end; i += 256)
    atomicAdd(&lcnt[ebuf[i] & 255u], 1);
  __syncthreads();
  int v = lcnt[tid];
  ts[tid] = v;
  __syncthreads();
  for (int off = 1; off < 256; off <<= 1) {
    int t = (tid >= off) ? ts[tid - off] : 0;
    __syncthreads();
    ts[tid] += t;
    __syncthreads();
  }
  int excl = start + ts[tid] - v;
  int node = (b << 8) + tid;
  if (node < N) row_start[node] = excl;
  lcur[tid] = excl;
  __syncthreads();
  for (int i = start + tid; i < end; i += 256) {
    unsigned int e = ebuf[i];
    int pos = atomicAdd(&lcur[e & 255u], 1);
    csr[pos] = e & ~255u;   // byte offset of source row (src * 256)
  }
}

// ---------------------------------------------------------------------------
// k_agg: 32 consecutive nodes per block (4 waves x 8 nodes serially). Per
// node: 2 edges/iter (each 32-lane half gathers one 256 B row at 8 B/lane),
// 8 edges unrolled; csr holds byte offsets (single 32-bit add per address).
// fp32 packed accumulate; halves combined via shfl_xor(32); fp8 mean written
// to LDS (stride 33 -> 2-way banks), then the block emits the fragment-linear
// group DIRECTLY (4 coalesced 1 KB store rounds) -- k_tr is fused away.
// ---------------------------------------------------------------------------
__global__ __launch_bounds__(256) void k_agg(
    const unsigned char* __restrict__ xqb, const unsigned int* __restrict__ csrb,
    const int* __restrict__ row_start, uint2* __restrict__ Aqagg, int N) {
  __shared__ uint2 ld[32][33];
  int tid = threadIdx.x;
  int lane = tid & 63;
  int w = tid >> 6;
  int half = lane >> 5;
  int l32 = lane & 31;
  int g0 = blockIdx.x * 32;
  unsigned lo = (unsigned)(l32 * 8);

  for (int nl = w * 8; nl < w * 8 + 8; nl++) {
    int wid = g0 + nl;
    int cw = (wid < N) ? wid : (N - 1);
    int start = row_start[cw];
    int end = row_start[cw + 1];
    int c = end - start;
    floatx2 a[4], b[4], d[4], e[4];
#pragma unroll
    for (int j = 0; j < 4; j++) {
      a[j] = (floatx2){0.f, 0.f}; b[j] = (floatx2){0.f, 0.f};
      d[j] = (floatx2){0.f, 0.f}; e[j] = (floatx2){0.f, 0.f};
    }
    int i = 0;
    for (; i + 8 <= c; i += 8) {
      unsigned o0 = csrb[start + i + half] + lo;
      unsigned o1 = csrb[start + i + 2 + half] + lo;
      unsigned o2 = csrb[start + i + 4 + half] + lo;
      unsigned o3 = csrb[start + i + 6 + half] + lo;
      uint2 v0 = *(const uint2*)(xqb + o0);
      uint2 v1 = *(const uint2*)(xqb + o1);
      uint2 v2 = *(const uint2*)(xqb + o2);
      uint2 v3 = *(const uint2*)(xqb + o3);
      acc8p(v0, a); acc8p(v1, b); acc8p(v2, d); acc8p(v3, e);
    }
    for (; i + 2 <= c; i += 2) {
      unsigned o0 = csrb[start + i + half] + lo;
      uint2 v0 = *(const uint2*)(xqb + o0);
      acc8p(v0, a);
    }
    if ((c & 1) && half == 0) {
      unsigned o0 = csrb[start + c - 1] + lo;
      uint2 v0 = *(const uint2*)(xqb + o0);
      acc8p(v0, a);
    }
#pragma unroll
    for (int j = 0; j < 4; j++) a[j] += b[j] + d[j] + e[j];

    float f[8];
#pragma unroll
    for (int j = 0; j < 4; j++) { f[2 * j] = a[j].x; f[2 * j + 1] = a[j].y; }
#pragma unroll
    for (int j = 0; j < 8; j++) f[j] += __shfl_xor(f[j], 32);

    if (half == 0) {
      float inv = 1.0f / fmaxf((float)c, 1.0f);
#pragma unroll
      for (int j = 0; j < 8; j++) f[j] *= inv;
      int lo0 = __builtin_amdgcn_cvt_pk_fp8_f32(f[0], f[1], 0, false);
      int w0  = __builtin_amdgcn_cvt_pk_fp8_f32(f[2], f[3], lo0, true);
      int lo1 = __builtin_amdgcn_cvt_pk_fp8_f32(f[4], f[5], 0, false);
      int w1  = __builtin_amdgcn_cvt_pk_fp8_f32(f[6], f[7], lo1, true);
      ld[nl][l32] = make_uint2((unsigned)w0, (unsigned)w1);
    }
  }
  __syncthreads();
  // emit fragment-linear group g = blockIdx.x (32 aligned nodes = 1 group)
  size_t obase = (size_t)blockIdx.x * 1024;
#pragma unroll
  for (int j = 0; j < 4; j++) {
    int oidx = j * 256 + tid;        // 0..1023
    int cc = oidx >> 6, hr = oidx & 63, hi = hr >> 5, row = hr & 31;
    Aqagg[obase + oidx] = ld[row][cc * 2 + hi];
  }
}

// ---------------------------------------------------------------------------
// k_h: block 128 rows x 128 cols, 4 waves 2x2, wave tile 64x64 (acc = 64
// regs). BK=64, 8 chunks, LDS double-buffered, one barrier per chunk;
// global_load_lds 1 KB wave-DMAs from fragment-linear fp8 A / bf16 B;
// lane-linear LDS consumes (2-way banks = free). 1D grid with the two
// col-halves of a row tile 8 blocks apart (same XCD back-to-back -> A-tile
// L2 reuse; R4-verified swizzle). Epilogue: plain partial stores.
// C/D: col=lane&31, row=(reg&3)+8*(reg>>2)+4*(lane>>5)  [m74/m101 verified]
// ---------------------------------------------------------------------------
__global__ __launch_bounds__(256, 3) void k_h(
    const unsigned char* __restrict__ Aqx, const unsigned char* __restrict__ Aqagg,
    const unsigned char* __restrict__ Bf8, const float* __restrict__ bself,
    const float* __restrict__ bnei, float* __restrict__ hpart, int N, int nfull) {
  __shared__ __align__(16) unsigned char As[2][8192];    // 16 KB
  __shared__ __align__(16) unsigned char Bs[2][16384];   // 32 KB
  __shared__ float colsum[128];
  int bid = blockIdx.x;
  int bx, by;
  if (bid < nfull) {
    bx = (bid >> 4) * 8 + (bid & 7);
    by = (bid >> 3) & 1;
  } else {
    int rem = bid - nfull;
    bx = (nfull >> 1) + (rem >> 1);
    by = rem & 1;
  }
  int tid = threadIdx.x;
  int lane = tid & 63;
  int w = tid >> 6;
  int wr = w >> 1, wc = w & 1;
  int l32 = lane & 31, half = lane >> 5;
  int rowBase = bx * 128;

  if (tid < 128) colsum[tid] = 0.f;

  floatx16 acc[2][2];
#pragma unroll
  for (int i = 0; i < 2; i++)
#pragma unroll
    for (int j = 0; j < 2; j++) acc[i][j] = (floatx16)(0.f);

  size_t a_grp = (size_t)(bx * 4 + w) * 16 * 512;
  int lb = lane * 16;

  // prologue: stage chunk 0
  {
    const unsigned char* asrc = Aqx + a_grp + lb;
    gl16(asrc, As[0] + w * 2048);
    gl16(asrc + 1024, As[0] + w * 2048 + 1024);
#pragma unroll
    for (int fi = 0; fi < 4; fi++) {
      int ctg = by * 4 + fi;
      gl16(Bf8 + (size_t)(w * 8 + ctg) * 1024 + lb, Bs[0] + (w * 4 + fi) * 1024);
    }
  }

  for (int ch = 0; ch < 8; ch++) {
    int buf = ch & 1;
    __syncthreads();
    if (ch < 7) {
      int cn = ch + 1;
      const unsigned char* Aq = (cn < 4) ? Aqx : Aqagg;
      const unsigned char* asrc = Aq + a_grp + (size_t)(cn & 3) * 2048 + lb;
      unsigned char* ad = As[buf ^ 1] + w * 2048;
      gl16(asrc, ad);
      gl16(asrc + 1024, ad + 1024);
#pragma unroll
      for (int fi = 0; fi < 4; fi++) {
        int cg = cn * 4 + w;
        int ctg = by * 4 + fi;
        gl16(Bf8 + (size_t)(cg * 8 + ctg) * 1024 + lb,
             Bs[buf ^ 1] + (w * 4 + fi) * 1024);
      }
    }
#pragma unroll
    for (int cl = 0; cl < 4; cl++) {
      short8 afr[2];
#pragma unroll
      for (int rt = 0; rt < 2; rt++) {
        uint2 av = *(const uint2*)&As[buf][(wr * 2 + rt) * 2048 + cl * 512 + lane * 8];
        afr[rt] = dec8(av);
      }
#pragma unroll
      for (int ctw = 0; ctw < 2; ctw++) {
        short8 bfr = *(const short8*)&Bs[buf][(cl * 4 + wc * 2 + ctw) * 1024 + lane * 16];
#pragma unroll
        for (int rt = 0; rt < 2; rt++)
          acc[rt][ctw] = __builtin_amdgcn_mfma_f32_32x32x16_bf16(
              afr[rt], bfr, acc[rt][ctw], 0, 0, 0);
      }
    }
  }

  // epilogue: bias + relu + row-masked column sums -> plain partial store
#pragma unroll
  for (int ctw = 0; ctw < 2; ctw++) {
    int lcol = (wc * 2 + ctw) * 32 + l32;
    int gcol = by * 128 + lcol;
    float bb = bself[gcol] + bnei[gcol];
    float psum = 0.f;
#pragma unroll
    for (int rt = 0; rt < 2; rt++) {
#pragma unroll
      for (int r = 0; r < 16; r++) {
        int rw = rowBase + wr * 64 + rt * 32 + (r & 3) + 8 * (r >> 2) + 4 * half;
        float v = acc[rt][ctw][r] + bb;
        v = v > 0.f ? v : 0.f;
        if (rw < N) psum += v;
      }
    }
    atomicAdd(&colsum[lcol], psum);   // LDS only (2 adds/col)
  }
  __syncthreads();
  if (tid < 128) hpart[(size_t)bx * 256 + by * 128 + tid] = colsum[tid];
}

// ---------------------------------------------------------------------------
// k_red: parallel reduction of hpart rows -> gsum. Coalesced 1 KB row reads,
// grid-stride; one global atomic per (block, column).
// ---------------------------------------------------------------------------
__global__ __launch_bounds__(256) void k_red(
    const float* __restrict__ hpart, float* __restrict__ gsum, int nbx) {
  int c = threadIdx.x;
  float s = 0.f;
  for (int i = blockIdx.x; i < nbx; i += gridDim.x)
    s += hpart[(size_t)i * 256 + c];
  atomicAdd(&gsum[c], s);
}

// ---------------------------------------------------------------------------
// k_out: out = (gsum / N) @ W_out + b_out   single block, 256 threads
// ---------------------------------------------------------------------------
__global__ __launch_bounds__(HID) void k_out(
    const float* __restrict__ gsum, const float* __restrict__ Wout,
    const float* __restrict__ bout, float* __restrict__ out, float invN) {
  __shared__ float g[HID];
  int c = threadIdx.x;
  g[c] = gsum[c] * invN;
  __syncthreads();
  float acc = bout[c];
#pragma unroll 8
  for (int k = 0; k < HID; k++) acc += g[k] * Wout[k * HID + c];
  out[c] = acc;
}

extern "C" void kernel_launch(void* const* d_in, const int* in_sizes, int n_in,
                              void* d_out, int out_size, void* d_ws, size_t ws_size,
                              hipStream_t stream) {
  const float* ns    = (const float*)d_in[0];
  const float* Win   = (const float*)d_in[1];
  const float* bin   = (const float*)d_in[2];
  const float* Wself = (const float*)d_in[3];
  const float* bself = (const float*)d_in[4];
  const float* Wnei  = (const float*)d_in[5];
  const float* bnei  = (const float*)d_in[6];
  const float* Wout  = (const float*)d_in[7];
  const float* bout  = (const float*)d_in[8];
  const int*   eidx  = (const int*)d_in[9];

  int N = in_sizes[0] / IND;
  int E = in_sizes[9] / 2;
  const int* src = eidx;
  const int* dst = eidx + E;
  int nb2 = (N + 255) >> 8;
  int nbx = (N + 127) / 128;                 // k_h row-tiles
  size_t NGU = (size_t)nbx * 4 * 16 * 64;    // fragment uint2 count (padded)

  // ws: xq | Aqx | Aqagg | Bf16 | csr | ebuf | row_start | bcnt | bbase |
  //     bcur | gsum | hpart
  unsigned int* xq     = (unsigned int*)d_ws;
  uint2* Aqx           = (uint2*)(xq + (size_t)N * 64);
  uint2* Aqagg         = Aqx + NGU;
  unsigned short* Bf16 = (unsigned short*)(Aqagg + NGU);
  unsigned int* csr  = (unsigned int*)(Bf16 + 256 * 512);
  unsigned int* ebuf = csr + E;
  int* row_start = (int*)(ebuf + E);
  int* bcnt      = row_start + N + 1;
  int* bbase     = bcnt + MAXB;
  int* bcur      = bbase + MAXB + 1;
  float* gsum    = (float*)(bcur + MAXB);
  float* hpart   = gsum + HID;

  hipMemsetAsync(bcnt, 0, MAXB * sizeof(int), stream);
  hipMemsetAsync(gsum, 0, HID * sizeof(float), stream);

  int G1 = (N + 7) / 8;
  int pgrid = (E + PB - 1) / PB;
  k_front<<<G1 + 256 + pgrid, 256, 0, stream>>>(
      ns, Win, bin, (uint2*)xq, Aqx, Wself, Wnei, Bf16, dst, bcnt,
      N, E, nb2, G1);

  k_bscan<<<1, 512, 0, stream>>>(bcnt, bbase, bcur, row_start, E, N, nb2);
  k_part<<<pgrid, 256, 0, stream>>>(src, dst, bcur, ebuf, E, nb2);
  k_fill2<<<nb2, 256, 0, stream>>>(ebuf, bbase, row_start, csr, N);

  int agrid = (N + 31) / 32;
  k_agg<<<agrid, 256, 0, stream>>>((const unsigned char*)xq, csr, row_start,
                                   Aqagg, N);

  int nblocks = nbx * 2;
  int nfull = (nblocks / 16) * 16;
  k_h<<<nblocks, 256, 0, stream>>>((const unsigned char*)Aqx,
                                   (const unsigned char*)Aqagg,
                                   (const unsigned char*)Bf16,
                                   bself, bnei, hpart, N, nfull);

  k_red<<<64, 256, 0, stream>>>(hpart, gsum, nbx);
  k_out<<<1, HID, 0, stream>>>(gsum, Wout, bout, (float*)d_out, 1.0f / (float)N);
}

// Round 19
// 290.375 us; speedup vs baseline: 1.6618x; 1.0104x over previous
//
#include <hip/hip_runtime.h>
#include <hip/hip_bf16.h>

#define HID 256
#define IND 21
#define PB 6400      // edges per block in k_part / bhist
#define MAXB 512     // max buckets (N <= 131072)

typedef short short8 __attribute__((ext_vector_type(8)));
typedef float floatx16 __attribute__((ext_vector_type(16)));
typedef float floatx2 __attribute__((ext_vector_type(2)));

__device__ inline unsigned short f2bf(float f) {
  __hip_bfloat16 h = __float2bfloat16(f);  // RNE
  union { __hip_bfloat16 h; unsigned short u; } c;
  c.h = h;
  return c.u;
}

// pack float2 -> 2 bf16 by truncation (exact for values that came from fp8)
__device__ inline unsigned int pk_bf16_trunc(floatx2 p) {
  union { float f; unsigned int u; } a, b;
  a.f = p.x; b.f = p.y;
  return (b.u & 0xffff0000u) | (a.u >> 16);
}

// accumulate 8 fp8 bytes into 4 packed-f32 accumulators
__device__ inline void acc8p(uint2 v, floatx2* a) {
  a[0] += __builtin_amdgcn_cvt_pk_f32_fp8((int)v.x, false);
  a[1] += __builtin_amdgcn_cvt_pk_f32_fp8((int)v.x, true);
  a[2] += __builtin_amdgcn_cvt_pk_f32_fp8((int)v.y, false);
  a[3] += __builtin_amdgcn_cvt_pk_f32_fp8((int)v.y, true);
}

__device__ inline short8 mk_s8(unsigned a, unsigned b, unsigned c, unsigned d) {
  union { uint4 u; short8 s; } x; x.u = make_uint4(a, b, c, d); return x.s;
}

// decode 8 fp8 bytes (uint2) -> short8 of bf16 (exact)
__device__ inline short8 dec8(uint2 v) {
  unsigned w0 = pk_bf16_trunc(__builtin_amdgcn_cvt_pk_f32_fp8((int)v.x, false));
  unsigned w1 = pk_bf16_trunc(__builtin_amdgcn_cvt_pk_f32_fp8((int)v.x, true));
  unsigned w2 = pk_bf16_trunc(__builtin_amdgcn_cvt_pk_f32_fp8((int)v.y, false));
  unsigned w3 = pk_bf16_trunc(__builtin_amdgcn_cvt_pk_f32_fp8((int)v.y, true));
  return mk_s8(w0, w1, w2, w3);
}

// async global->LDS DMA, 16 B/lane. LDS dest = (uniform) base + lane*16.
__device__ inline void gl16(const unsigned char* g, unsigned char* l) {
  __builtin_amdgcn_global_load_lds(
      (const __attribute__((address_space(1))) unsigned char*)g,
      (__attribute__((address_space(3))) unsigned char*)l, 16, 0, 0);
}

// ---------------------------------------------------------------------------
// fused front kernel: [0,G1) linear_in | [G1,G1+256) wconv | rest bhist
// linear_in pack phase: thread = (node j = tid&7, unit u = tid>>3) -> LDS
// reads 2-way-bank-free; one uint2 pack serves BOTH row-major xq and
// fragment-linear Aqx with 64 B-dense wave writes.
// wconv writes B fragment-linear:
//   Bf16[((c*8+ct)*64 + lane)*8 + j] = W[c*16+(lane>>5)*8+j][ct*32+(lane&31)]
// ---------------------------------------------------------------------------
__global__ __launch_bounds__(256) void k_front(
    const float* __restrict__ ns, const float* __restrict__ Win,
    const float* __restrict__ bin, uint2* __restrict__ xq2,
    uint2* __restrict__ Aqx,
    const float* __restrict__ Wself, const float* __restrict__ Wnei,
    unsigned short* __restrict__ Bf16,
    const int* __restrict__ dst, int* __restrict__ bcnt,
    int N, int E, int nb2, int G1) {
  int blk = blockIdx.x;
  int tid = threadIdx.x;
  if (blk < G1) {
    __shared__ float s[8][IND];
    __shared__ float fx[8][257];
    int nb = blk * 8;
    if (tid < 8 * IND) {
      int idx = nb * IND + tid;
      s[tid / IND][tid % IND] = (idx < N * IND) ? ns[idx] : 0.f;
    }
    float w[IND];
#pragma unroll
    for (int k = 0; k < IND; k++) w[k] = Win[k * HID + tid];
    float b = bin[tid];
    __syncthreads();
#pragma unroll
    for (int j = 0; j < 8; j++) {
      float acc = b;
#pragma unroll
      for (int k = 0; k < IND; k++) acc += s[j][k] * w[k];
      fx[j][tid] = acc > 0.f ? acc : 0.f;
    }
    __syncthreads();
    // pack: one uint2 (8 fp8) per thread -> xq (row-major) + Aqx (fragment)
    {
      int j = tid & 7, u = tid >> 3;    // node-local, 8-col unit 0..31
      int node = nb + j;
      if (node < N) {
        const float* fp = &fx[j][u * 8];
        int lo0 = __builtin_amdgcn_cvt_pk_fp8_f32(fp[0], fp[1], 0, false);
        int w0  = __builtin_amdgcn_cvt_pk_fp8_f32(fp[2], fp[3], lo0, true);
        int lo1 = __builtin_amdgcn_cvt_pk_fp8_f32(fp[4], fp[5], 0, false);
        int w1  = __builtin_amdgcn_cvt_pk_fp8_f32(fp[6], fp[7], lo1, true);
        uint2 val = make_uint2((unsigned)w0, (unsigned)w1);
        xq2[(size_t)node * 32 + u] = val;
        int g = node >> 5, row = node & 31, c = u >> 1, hi = u & 1;
        Aqx[(size_t)(g * 16 + c) * 64 + hi * 32 + row] = val;
      }
    }
  } else if (blk < G1 + 256) {
    int n = blk - G1;           // output column 0..255
    int ct = n >> 5, l5 = n & 31;
#pragma unroll
    for (int t = 0; t < 2; t++) {
      int k = tid + t * 256;    // 0..511
      float v = (k < HID) ? Wself[k * HID + n] : Wnei[(k - HID) * HID + n];
      int c = k >> 4, kin = k & 15;
      int lane = (kin >> 3) * 32 + l5;
      int j = kin & 7;
      Bf16[(size_t)((c * 8 + ct) * 64 + lane) * 8 + j] = f2bf(v);
    }
  } else {
    __shared__ int lh[MAXB];
    int e0 = (blk - G1 - 256) * PB;
    for (int b = tid; b < nb2; b += 256) lh[b] = 0;
    __syncthreads();
    int c = min(PB, E - e0);
    for (int i = tid; i < c; i += 256) atomicAdd(&lh[dst[e0 + i] >> 8], 1);
    __syncthreads();
    for (int b = tid; b < nb2; b += 256)
      if (lh[b]) atomicAdd(&bcnt[b], lh[b]);
  }
}

__global__ __launch_bounds__(512) void k_bscan(
    const int* __restrict__ bcnt, int* __restrict__ bbase, int* __restrict__ bcur,
    int* __restrict__ row_start, int E, int N, int nb2) {
  __shared__ int ts[512];
  int tid = threadIdx.x;
  int v = (tid < nb2) ? bcnt[tid] : 0;
  ts[tid] = v;
  __syncthreads();
  for (int off = 1; off < 512; off <<= 1) {
    int t = (tid >= off) ? ts[tid - off] : 0;
    __syncthreads();
    ts[tid] += t;
    __syncthreads();
  }
  if (tid < nb2) { bbase[tid] = ts[tid] - v; bcur[tid] = ts[tid] - v; }
  if (tid == 0) { bbase[nb2] = E; row_start[N] = E; }
}

// partition edges into per-bucket regions of ebuf (bucket = dst>>8).
// ebuf entry packed: (src << 8) | (dst & 255) -- 4 B/edge.
__global__ __launch_bounds__(256) void k_part(
    const int* __restrict__ src, const int* __restrict__ dst,
    int* __restrict__ bcur, unsigned int* __restrict__ ebuf, int E, int nb2) {
  __shared__ int lh[MAXB];
  int tid = threadIdx.x;
  int e0 = blockIdx.x * PB;
  for (int b = tid; b < nb2; b += 256) lh[b] = 0;
  __syncthreads();
  int cnt = min(PB, E - e0);
  for (int i = tid; i < cnt; i += 256) atomicAdd(&lh[dst[e0 + i] >> 8], 1);
  __syncthreads();
  for (int b = tid; b < nb2; b += 256) {
    int c = lh[b];
    lh[b] = (c > 0) ? atomicAdd(&bcur[b], c) : 0;
  }
  __syncthreads();
  for (int i = tid; i < cnt; i += 256) {
    int s = src[e0 + i];
    int d = dst[e0 + i];
    int pos = atomicAdd(&lh[d >> 8], 1);
    ebuf[pos] = ((unsigned)s << 8) | ((unsigned)d & 255u);
  }
}

// one block per bucket: LDS count + scan -> row_start; LDS cursors -> csr.
// csr stores the BYTE OFFSET of the source row (src*256 == e & ~255).
__global__ __launch_bounds__(256) void k_fill2(
    const unsigned int* __restrict__ ebuf, const int* __restrict__ bbase,
    int* __restrict__ row_start, unsigned int* __restrict__ csr, int N) {
  __shared__ int lcnt[256];
  __shared__ int lcur[256];
  __shared__ int ts[256];
  int b = blockIdx.x;
  int tid = threadIdx.x;
  int start = bbase[b], end = bbase[b + 1];
  lcnt[tid] = 0;
  __syncthreads();
  for (int i = start + tid; i < end; i += 256)
    atomicAdd(&lcnt[ebuf[i] & 255u], 1);
  __syncthreads();
  int v = lcnt[tid];
  ts[tid] = v;
  __syncthreads();
  for (int off = 1; off < 256; off <<= 1) {
    int t = (tid >= off) ? ts[tid - off] : 0;
    __syncthreads();
    ts[tid] += t;
    __syncthreads();
  }
  int excl = start + ts[tid] - v;
  int node = (b << 8) + tid;
  if (node < N) row_start[node] = excl;
  lcur[tid] = excl;
  __syncthreads();
  for (int i = start + tid; i < end; i += 256) {
    unsigned int e = ebuf[i];
    int pos = atomicAdd(&lcur[e & 255u], 1);
    csr[pos] = e & ~255u;   // byte offset of source row (src * 256)
  }
}

// ---------------------------------------------------------------------------
// k_agg: 32 consecutive nodes per block (4 waves x 4 iterations x 2 nodes).
// ONE NODE PER 32-LANE HALF: each half accumulates all edges of its own node
// (4-deep load unroll, 8 B/lane over a 256 B row) -- no cross-half shfl at
// all. csr holds byte offsets (single 32-bit add per address). fp8 mean goes
// to LDS (stride 33 -> 2-way banks); block emits the fragment-linear group
// directly (4 coalesced 1 KB store rounds).
// ---------------------------------------------------------------------------
__global__ __launch_bounds__(256) void k_agg(
    const unsigned char* __restrict__ xqb, const unsigned int* __restrict__ csrb,
    const int* __restrict__ row_start, uint2* __restrict__ Aqagg, int N) {
  __shared__ uint2 ld[32][33];
  int tid = threadIdx.x;
  int lane = tid & 63;
  int w = tid >> 6;
  int half = lane >> 5;
  int l32 = lane & 31;
  int g0 = blockIdx.x * 32;
  unsigned lo = (unsigned)(l32 * 8);

#pragma unroll
  for (int it = 0; it < 4; it++) {
    int nl = w * 8 + it * 2 + half;   // this half's node (0..31 in block)
    int wid = g0 + nl;
    int cw = (wid < N) ? wid : (N - 1);
    int start = row_start[cw];
    int end = row_start[cw + 1];
    int c = end - start;
    floatx2 a[4], b[4], d[4], e[4];
#pragma unroll
    for (int j = 0; j < 4; j++) {
      a[j] = (floatx2){0.f, 0.f}; b[j] = (floatx2){0.f, 0.f};
      d[j] = (floatx2){0.f, 0.f}; e[j] = (floatx2){0.f, 0.f};
    }
    int i = 0;
    for (; i + 4 <= c; i += 4) {
      unsigned o0 = csrb[start + i] + lo;
      unsigned o1 = csrb[start + i + 1] + lo;
      unsigned o2 = csrb[start + i + 2] + lo;
      unsigned o3 = csrb[start + i + 3] + lo;
      uint2 v0 = *(const uint2*)(xqb + o0);
      uint2 v1 = *(const uint2*)(xqb + o1);
      uint2 v2 = *(const uint2*)(xqb + o2);
      uint2 v3 = *(const uint2*)(xqb + o3);
      acc8p(v0, a); acc8p(v1, b); acc8p(v2, d); acc8p(v3, e);
    }
    for (; i < c; i++) {
      unsigned o0 = csrb[start + i] + lo;
      uint2 v0 = *(const uint2*)(xqb + o0);
      acc8p(v0, a);
    }
#pragma unroll
    for (int j = 0; j < 4; j++) a[j] += b[j] + d[j] + e[j];

    float inv = 1.0f / fmaxf((float)c, 1.0f);
    float f[8];
#pragma unroll
    for (int j = 0; j < 4; j++) {
      f[2 * j] = a[j].x * inv;
      f[2 * j + 1] = a[j].y * inv;
    }
    int lo0 = __builtin_amdgcn_cvt_pk_fp8_f32(f[0], f[1], 0, false);
    int w0  = __builtin_amdgcn_cvt_pk_fp8_f32(f[2], f[3], lo0, true);
    int lo1 = __builtin_amdgcn_cvt_pk_fp8_f32(f[4], f[5], 0, false);
    int w1  = __builtin_amdgcn_cvt_pk_fp8_f32(f[6], f[7], lo1, true);
    ld[nl][l32] = make_uint2((unsigned)w0, (unsigned)w1);
  }
  __syncthreads();
  // emit fragment-linear group g = blockIdx.x (32 aligned nodes = 1 group)
  size_t obase = (size_t)blockIdx.x * 1024;
#pragma unroll
  for (int j = 0; j < 4; j++) {
    int oidx = j * 256 + tid;        // 0..1023
    int cc = oidx >> 6, hr = oidx & 63, hi = hr >> 5, row = hr & 31;
    Aqagg[obase + oidx] = ld[row][cc * 2 + hi];
  }
}

// ---------------------------------------------------------------------------
// k_h: block 128 rows x 128 cols, 4 waves 2x2, wave tile 64x64 (acc = 64
// regs). BK=64, 8 chunks, LDS double-buffered, one barrier per chunk;
// global_load_lds 1 KB wave-DMAs from fragment-linear fp8 A / bf16 B;
// lane-linear LDS consumes (2-way banks = free). 1D grid with the two
// col-halves of a row tile 8 blocks apart (same XCD back-to-back -> A-tile
// L2 reuse). Epilogue: plain partial stores.
// C/D: col=lane&31, row=(reg&3)+8*(reg>>2)+4*(lane>>5)  [m74/m101 verified]
// ---------------------------------------------------------------------------
__global__ __launch_bounds__(256, 3) void k_h(
    const unsigned char* __restrict__ Aqx, const unsigned char* __restrict__ Aqagg,
    const unsigned char* __restrict__ Bf8, const float* __restrict__ bself,
    const float* __restrict__ bnei, float* __restrict__ hpart, int N, int nfull) {
  __shared__ __align__(16) unsigned char As[2][8192];    // 16 KB
  __shared__ __align__(16) unsigned char Bs[2][16384];   // 32 KB
  __shared__ float colsum[128];
  int bid = blockIdx.x;
  int bx, by;
  if (bid < nfull) {
    bx = (bid >> 4) * 8 + (bid & 7);
    by = (bid >> 3) & 1;
  } else {
    int rem = bid - nfull;
    bx = (nfull >> 1) + (rem >> 1);
    by = rem & 1;
  }
  int tid = threadIdx.x;
  int lane = tid & 63;
  int w = tid >> 6;
  int wr = w >> 1, wc = w & 1;
  int l32 = lane & 31, half = lane >> 5;
  int rowBase = bx * 128;

  if (tid < 128) colsum[tid] = 0.f;

  floatx16 acc[2][2];
#pragma unroll
  for (int i = 0; i < 2; i++)
#pragma unroll
    for (int j = 0; j < 2; j++) acc[i][j] = (floatx16)(0.f);

  size_t a_grp = (size_t)(bx * 4 + w) * 16 * 512;
  int lb = lane * 16;

  // prologue: stage chunk 0
  {
    const unsigned char* asrc = Aqx + a_grp + lb;
    gl16(asrc, As[0] + w * 2048);
    gl16(asrc + 1024, As[0] + w * 2048 + 1024);
#pragma unroll
    for (int fi = 0; fi < 4; fi++) {
      int ctg = by * 4 + fi;
      gl16(Bf8 + (size_t)(w * 8 + ctg) * 1024 + lb, Bs[0] + (w * 4 + fi) * 1024);
    }
  }

  for (int ch = 0; ch < 8; ch++) {
    int buf = ch & 1;
    __syncthreads();
    if (ch < 7) {
      int cn = ch + 1;
      const unsigned char* Aq = (cn < 4) ? Aqx : Aqagg;
      const unsigned char* asrc = Aq + a_grp + (size_t)(cn & 3) * 2048 + lb;
      unsigned char* ad = As[buf ^ 1] + w * 2048;
      gl16(asrc, ad);
      gl16(asrc + 1024, ad + 1024);
#pragma unroll
      for (int fi = 0; fi < 4; fi++) {
        int cg = cn * 4 + w;
        int ctg = by * 4 + fi;
        gl16(Bf8 + (size_t)(cg * 8 + ctg) * 1024 + lb,
             Bs[buf ^ 1] + (w * 4 + fi) * 1024);
      }
    }
#pragma unroll
    for (int cl = 0; cl < 4; cl++) {
      short8 afr[2];
#pragma unroll
      for (int rt = 0; rt < 2; rt++) {
        uint2 av = *(const uint2*)&As[buf][(wr * 2 + rt) * 2048 + cl * 512 + lane * 8];
        afr[rt] = dec8(av);
      }
#pragma unroll
      for (int ctw = 0; ctw < 2; ctw++) {
        short8 bfr = *(const short8*)&Bs[buf][(cl * 4 + wc * 2 + ctw) * 1024 + lane * 16];
#pragma unroll
        for (int rt = 0; rt < 2; rt++)
          acc[rt][ctw] = __builtin_amdgcn_mfma_f32_32x32x16_bf16(
              afr[rt], bfr, acc[rt][ctw], 0, 0, 0);
      }
    }
  }

  // epilogue: bias + relu + row-masked column sums -> plain partial store
#pragma unroll
  for (int ctw = 0; ctw < 2; ctw++) {
    int lcol = (wc * 2 + ctw) * 32 + l32;
    int gcol = by * 128 + lcol;
    float bb = bself[gcol] + bnei[gcol];
    float psum = 0.f;
#pragma unroll
    for (int rt = 0; rt < 2; rt++) {
#pragma unroll
      for (int r = 0; r < 16; r++) {
        int rw = rowBase + wr * 64 + rt * 32 + (r & 3) + 8 * (r >> 2) + 4 * half;
        float v = acc[rt][ctw][r] + bb;
        v = v > 0.f ? v : 0.f;
        if (rw < N) psum += v;
      }
    }
    atomicAdd(&colsum[lcol], psum);   // LDS only (2 adds/col)
  }
  __syncthreads();
  if (tid < 128) hpart[(size_t)bx * 256 + by * 128 + tid] = colsum[tid];
}

// ---------------------------------------------------------------------------
// k_red: parallel reduction of hpart rows -> gsum. Coalesced 1 KB row reads,
// grid-stride; one global atomic per (block, column).
// ---------------------------------------------------------------------------
__global__ __launch_bounds__(256) void k_red(
    const float* __restrict__ hpart, float* __restrict__ gsum, int nbx) {
  int c = threadIdx.x;
  float s = 0.f;
  for (int i = blockIdx.x; i < nbx; i += gridDim.x)
    s += hpart[(size_t)i * 256 + c];
  atomicAdd(&gsum[c], s);
}

// ---------------------------------------------------------------------------
// k_out: out = (gsum / N) @ W_out + b_out   single block, 256 threads
// ---------------------------------------------------------------------------
__global__ __launch_bounds__(HID) void k_out(
    const float* __restrict__ gsum, const float* __restrict__ Wout,
    const float* __restrict__ bout, float* __restrict__ out, float invN) {
  __shared__ float g[HID];
  int c = threadIdx.x;
  g[c] = gsum[c] * invN;
  __syncthreads();
  float acc = bout[c];
#pragma unroll 8
  for (int k = 0; k < HID; k++) acc += g[k] * Wout[k * HID + c];
  out[c] = acc;
}

extern "C" void kernel_launch(void* const* d_in, const int* in_sizes, int n_in,
                              void* d_out, int out_size, void* d_ws, size_t ws_size,
                              hipStream_t stream) {
  const float* ns    = (const float*)d_in[0];
  const float* Win   = (const float*)d_in[1];
  const float* bin   = (const float*)d_in[2];
  const float* Wself = (const float*)d_in[3];
  const float* bself = (const float*)d_in[4];
  const float* Wnei  = (const float*)d_in[5];
  const float* bnei  = (const float*)d_in[6];
  const float* Wout  = (const float*)d_in[7];
  const float* bout  = (const float*)d_in[8];
  const int*   eidx  = (const int*)d_in[9];

  int N = in_sizes[0] / IND;
  int E = in_sizes[9] / 2;
  const int* src = eidx;
  const int* dst = eidx + E;
  int nb2 = (N + 255) >> 8;
  int nbx = (N + 127) / 128;                 // k_h row-tiles
  size_t NGU = (size_t)nbx * 4 * 16 * 64;    // fragment uint2 count (padded)

  // ws: xq | Aqx | Aqagg | Bf16 | csr | ebuf | row_start | bcnt | bbase |
  //     bcur | gsum | hpart
  unsigned int* xq     = (unsigned int*)d_ws;
  uint2* Aqx           = (uint2*)(xq + (size_t)N * 64);
  uint2* Aqagg         = Aqx + NGU;
  unsigned short* Bf16 = (unsigned short*)(Aqagg + NGU);
  unsigned int* csr  = (unsigned int*)(Bf16 + 256 * 512);
  unsigned int* ebuf = csr + E;
  int* row_start = (int*)(ebuf + E);
  int* bcnt      = row_start + N + 1;
  int* bbase     = bcnt + MAXB;
  int* bcur      = bbase + MAXB + 1;
  float* gsum    = (float*)(bcur + MAXB);
  float* hpart   = gsum + HID;

  hipMemsetAsync(bcnt, 0, MAXB * sizeof(int), stream);
  hipMemsetAsync(gsum, 0, HID * sizeof(float), stream);

  int G1 = (N + 7) / 8;
  int pgrid = (E + PB - 1) / PB;
  k_front<<<G1 + 256 + pgrid, 256, 0, stream>>>(
      ns, Win, bin, (uint2*)xq, Aqx, Wself, Wnei, Bf16, dst, bcnt,
      N, E, nb2, G1);

  k_bscan<<<1, 512, 0, stream>>>(bcnt, bbase, bcur, row_start, E, N, nb2);
  k_part<<<pgrid, 256, 0, stream>>>(src, dst, bcur, ebuf, E, nb2);
  k_fill2<<<nb2, 256, 0, stream>>>(ebuf, bbase, row_start, csr, N);

  int agrid = (N + 31) / 32;
  k_agg<<<agrid, 256, 0, stream>>>((const unsigned char*)xq, csr, row_start,
                                   Aqagg, N);

  int nblocks = nbx * 2;
  int nfull = (nblocks / 16) * 16;
  k_h<<<nblocks, 256, 0, stream>>>((const unsigned char*)Aqx,
                                   (const unsigned char*)Aqagg,
                                   (const unsigned char*)Bf16,
                                   bself, bnei, hpart, N, nfull);

  k_red<<<64, 256, 0, stream>>>(hpart, gsum, nbx);
  k_out<<<1, HID, 0, stream>>>(gsum, Wout, bout, (float*)d_out, 1.0f / (float)N);
}